// Round 4
// baseline (798.431 us; speedup 1.0000x reference)
//
#include <hip/hip_runtime.h>

#define NFEAT 256
#define DHEAD 64
#define NSEQ  4096

constexpr float NORM_C  = 0.35355339059327373f;  // 64^-0.25
constexpr float RATIO_C = 0.0625f;               // 256^-0.5
constexpr float DIAG_C  = 0.0625f;               // 0.5 * 64^-0.5
constexpr float KEPS_C  = 1e-4f;

using v8s = __attribute__((ext_vector_type(8))) short;
using v4s = __attribute__((ext_vector_type(4))) short;
using v4f = __attribute__((ext_vector_type(4))) float;
union Frag8 { v8s v; ushort u[8]; };
union Frag4 { v4s v; ushort u[4]; };

__device__ __forceinline__ ushort bf16h(float x) {
  unsigned u = __float_as_uint(x);
  return (ushort)((u + 0x7FFFu + ((u >> 16) & 1)) >> 16);
}
__device__ __forceinline__ float bf16f(ushort h) {
  return __uint_as_float(((unsigned)h) << 16);
}
__device__ __forceinline__ unsigned enc_f(float f) {
  unsigned u = __float_as_uint(f);
  return (u & 0x80000000u) ? ~u : (u | 0x80000000u);
}
__device__ __forceinline__ float dec_f(unsigned e) {
  return (e & 0x80000000u) ? __uint_as_float(e ^ 0x80000000u) : __uint_as_float(~e);
}

#define MFMA32(a, b, c) __builtin_amdgcn_mfma_f32_16x16x32_bf16((a), (b), (c), 0, 0, 0)
// gfx90a+/gfx950 K=16 bf16 MFMA (v_mfma_f32_16x16x16_bf16; V4s operands).
// __has_builtin is unreliable in the HIP host pass -> guard on device compile;
// host pass only needs to parse.
#if defined(__HIP_DEVICE_COMPILE__)
#define MFMA16(a, b, c) __builtin_amdgcn_mfma_f32_16x16x16bf16_1k((a), (b), (c), 0, 0, 0)
#else
#define MFMA16(a, b, c) (c)
#endif

// P (NORM folded) -> bf16 hi/lo planes, FRAGMENT-MAJOR:
//   P2[(d>>3)*256*8 + j*8 + (d&7)]
// A-frag and B-frag layouts are symmetric (row/col = lane&15, k = q*8+i),
// so the same bytes serve P as either operand.
__global__ void prep_kernel(const float* __restrict__ proj,
                            ushort* __restrict__ P2hi, ushort* __restrict__ P2lo) {
  int i = blockIdx.x * 256 + threadIdx.x;
  if (i < NFEAT * DHEAD) {
    int j = i >> 6, d = i & 63;
    float x = NORM_C * proj[i];
    ushort h = bf16h(x);
    int off = ((d >> 3) * NFEAT + j) * 8 + (d & 7);
    P2hi[off] = h;
    P2lo[off] = bf16h(x - bf16f(h));
  }
}

// ---------------------------------------------------------------------------
// kmax: global max of dd_k via ddT MFMA (A=P, B=K-rows), single bf16 plane.
// 256 blocks x 1024 thr (16 waves), wave-independent, zero main-loop barriers.
// Each wave: 2 steps of 16 rows, full j=256 (acc[16]).
// ---------------------------------------------------------------------------
__global__ __launch_bounds__(1024, 4) void kmax_kernel(
    const float* __restrict__ kk, const ushort* __restrict__ P2hi,
    unsigned* __restrict__ kmax_u) {
  __shared__ __align__(16) ushort PhiL[NFEAT * DHEAD];  // 32 KB
  const int t = threadIdx.x, lane = t & 63, w = t >> 6;
  const int cl = lane & 15, q = lane >> 4;
  const int head = blockIdx.x >> 3, slab = blockIdx.x & 7;
  for (int i = t; i < 2048; i += 1024)
    ((float4*)PhiL)[i] = ((const float4*)P2hi)[i];
  __syncthreads();
  float mx = -3.0e38f;
  for (int s = 0; s < 2; ++s) {
    const int rb = slab * 512 + (w + s * 16) * 16;
    const float* xb = kk + ((size_t)(head * NSEQ + rb + cl)) * DHEAD + q * 8;
    float4 pa0 = *(const float4*)(xb);
    float4 pa1 = *(const float4*)(xb + 4);
    float4 pa2 = *(const float4*)(xb + 32);
    float4 pa3 = *(const float4*)(xb + 36);
    float af[2][8] = {{pa0.x, pa0.y, pa0.z, pa0.w, pa1.x, pa1.y, pa1.z, pa1.w},
                      {pa2.x, pa2.y, pa2.z, pa2.w, pa3.x, pa3.y, pa3.z, pa3.w}};
    Frag8 bh[2];
#pragma unroll
    for (int ks = 0; ks < 2; ++ks)
#pragma unroll
      for (int i = 0; i < 8; ++i) bh[ks].u[i] = bf16h(af[ks][i]);
    v4f acc[16];
#pragma unroll
    for (int jt = 0; jt < 16; ++jt) acc[jt] = (v4f){0.f, 0.f, 0.f, 0.f};
#pragma unroll
    for (int ks = 0; ks < 2; ++ks)
#pragma unroll
      for (int jt = 0; jt < 16; ++jt) {
        v8s pA = *(const v8s*)&PhiL[((ks * 4 + q) * NFEAT + jt * 16 + cl) * 8];
        acc[jt] = MFMA32(pA, bh[ks].v, acc[jt]);
      }
#pragma unroll
    for (int jt = 0; jt < 16; ++jt)
#pragma unroll
      for (int r = 0; r < 4; ++r) mx = fmaxf(mx, acc[jt][r]);
  }
  for (int s = 1; s < 64; s <<= 1) mx = fmaxf(mx, __shfl_xor(mx, s));
  if (lane == 0) atomicMax(kmax_u, enc_f(mx));
}

// ---------------------------------------------------------------------------
// kctx: dd_k (rows as M) -> kp in registers -> ctx += kp^T * V via the
// transpose trick (C-layout of dd == A-frag layout of the K=16 MFMA).
// 256 blocks x 1024 thr; wave = (jq = w&3 j-quarter, rg = w>>2 row-group);
// 8 chunks of 16 rows per wave. Zero main-loop barriers. LDS = P only (64 KB).
// ---------------------------------------------------------------------------
__global__ __launch_bounds__(1024, 4) void kctx_kernel(
    const float* __restrict__ kk, const float* __restrict__ vv,
    const ushort* __restrict__ P2hi, const ushort* __restrict__ P2lo,
    const unsigned* __restrict__ kmax_u, float* __restrict__ ksum,
    float* __restrict__ ctx) {
  __shared__ __align__(16) ushort PhiL[NFEAT * DHEAD];  // 32 KB
  __shared__ __align__(16) ushort PloL[NFEAT * DHEAD];  // 32 KB
  const int t = threadIdx.x, lane = t & 63, w = t >> 6;
  const int cl = lane & 15, q = lane >> 4;
  const int jq = w & 3, rg = w >> 2;
  const int head = blockIdx.x >> 3, slab = blockIdx.x & 7;
  const float m = dec_f(*kmax_u);
  for (int i = t; i < 2048; i += 1024) {
    ((float4*)PhiL)[i] = ((const float4*)P2hi)[i];
    ((float4*)PloL)[i] = ((const float4*)P2lo)[i];
  }
  __syncthreads();
  float ksacc[4] = {0.f, 0.f, 0.f, 0.f};
  v4f ctxacc[4][4];
#pragma unroll
  for (int jt = 0; jt < 4; ++jt)
#pragma unroll
    for (int et = 0; et < 4; ++et) ctxacc[jt][et] = (v4f){0.f, 0.f, 0.f, 0.f};

  for (int cc = 0; cc < 8; ++cc) {
    const int rb = slab * 512 + (rg + cc * 4) * 16;
    // A-frags: K rows (row = cl), k = d
    const float* xb = kk + ((size_t)(head * NSEQ + rb + cl)) * DHEAD + q * 8;
    float4 pa0 = *(const float4*)(xb);
    float4 pa1 = *(const float4*)(xb + 4);
    float4 pa2 = *(const float4*)(xb + 32);
    float4 pa3 = *(const float4*)(xb + 36);
    float af[2][8] = {{pa0.x, pa0.y, pa0.z, pa0.w, pa1.x, pa1.y, pa1.z, pa1.w},
                      {pa2.x, pa2.y, pa2.z, pa2.w, pa3.x, pa3.y, pa3.z, pa3.w}};
    Frag8 ah[2], al[2];
    float ssq = 0.f;
#pragma unroll
    for (int ks = 0; ks < 2; ++ks)
#pragma unroll
      for (int i = 0; i < 8; ++i) {
        float x = af[ks][i];
        ssq = fmaf(x, x, ssq);
        ushort h = bf16h(x);
        ah[ks].u[i] = h;
        al[ks].u[i] = bf16h(x - bf16f(h));
      }
    float s2 = ssq;
    s2 += __shfl_xor(s2, 16);
    s2 += __shfl_xor(s2, 32);  // full ssq of row cl at every lane
    // dd: M=rows, N=j-quarter. C: lane(cl,q) = dd[n=q*4+r][j=jq*64+jt*16+cl]
    v4f acc[4];
#pragma unroll
    for (int jt = 0; jt < 4; ++jt) acc[jt] = (v4f){0.f, 0.f, 0.f, 0.f};
#pragma unroll
    for (int ks = 0; ks < 2; ++ks)
#pragma unroll
      for (int jt = 0; jt < 4; ++jt) {
        const int pidx = ((ks * 4 + q) * NFEAT + jq * 64 + jt * 16 + cl) * 8;
        v8s bh = *(const v8s*)&PhiL[pidx];
        v8s bl = *(const v8s*)&PloL[pidx];
        acc[jt] = MFMA32(ah[ks].v, bh, acc[jt]);
        acc[jt] = MFMA32(ah[ks].v, bl, acc[jt]);
        acc[jt] = MFMA32(al[ks].v, bh, acc[jt]);
      }
    float dg[4];
#pragma unroll
    for (int r = 0; r < 4; ++r) dg[r] = DIAG_C * __shfl(s2, q * 4 + r);
    // kp in registers; C-layout == A-frag layout of MFMA16 (k = n = q*4+i)
    Frag4 kph[4], kpl[4];
#pragma unroll
    for (int jt = 0; jt < 4; ++jt)
#pragma unroll
      for (int r = 0; r < 4; ++r) {
        float e_ = RATIO_C * (__expf(acc[jt][r] - dg[r] - m) + KEPS_C);
        ksacc[jt] += e_;
        ushort h = bf16h(e_);
        kph[jt].u[r] = h;
        kpl[jt].u[r] = bf16h(e_ - bf16f(h));
      }
    // ctx += kp^T * V;  B-frag: V[rb + q*4+i][et*16+cl]
    const float* vb = vv + ((size_t)(head * NSEQ + rb + q * 4)) * DHEAD + cl;
#pragma unroll
    for (int et = 0; et < 4; ++et) {
      Frag4 bvh, bvl;
#pragma unroll
      for (int i = 0; i < 4; ++i) {
        float x = vb[(size_t)i * DHEAD + et * 16];
        ushort h = bf16h(x);
        bvh.u[i] = h;
        bvl.u[i] = bf16h(x - bf16f(h));
      }
#pragma unroll
      for (int jt = 0; jt < 4; ++jt) {
        ctxacc[jt][et] = MFMA16(kph[jt].v, bvh.v, ctxacc[jt][et]);
        ctxacc[jt][et] = MFMA16(kph[jt].v, bvl.v, ctxacc[jt][et]);
        ctxacc[jt][et] = MFMA16(kpl[jt].v, bvh.v, ctxacc[jt][et]);
      }
    }
  }
#pragma unroll
  for (int jt = 0; jt < 4; ++jt) {
    float s = ksacc[jt];
    s += __shfl_xor(s, 16);
    s += __shfl_xor(s, 32);
    if (q == 0) atomicAdd(&ksum[head * NFEAT + jq * 64 + jt * 16 + cl], s);
  }
#pragma unroll
  for (int jt = 0; jt < 4; ++jt)
#pragma unroll
    for (int et = 0; et < 4; ++et)
#pragma unroll
      for (int r = 0; r < 4; ++r) {
        int j = jq * 64 + jt * 16 + q * 4 + r;
        int e = et * 16 + cl;
        atomicAdd(&ctx[((size_t)head * NFEAT + j) * DHEAD + e],
                  ctxacc[jt][et][r]);
      }
}

// ---------------------------------------------------------------------------
// ctxprep: ctx fp32 [h][j][e] -> ctxT bf16 hi/lo planes [h][e][j]
// ---------------------------------------------------------------------------
__global__ void ctxprep_kernel(const float* __restrict__ ctx,
                               ushort* __restrict__ ctxThi,
                               ushort* __restrict__ ctxTlo) {
  __shared__ float tile[64 * 65];
  const int head = blockIdx.x >> 2, jb = blockIdx.x & 3, t = threadIdx.x;
#pragma unroll
  for (int i = 0; i < 16; ++i) {
    int idx = t + i * 256;
    int jj = idx >> 6, e = idx & 63;
    tile[jj * 65 + e] = ctx[((size_t)head * NFEAT + jb * 64 + jj) * DHEAD + e];
  }
  __syncthreads();
#pragma unroll
  for (int i = 0; i < 16; ++i) {
    int idx = t + i * 256;
    int e = idx >> 6, jj = idx & 63;
    float x = tile[jj * 65 + e];
    ushort h = bf16h(x);
    size_t o = ((size_t)head * DHEAD + e) * NFEAT + jb * 64 + jj;
    ctxThi[o] = h;
    ctxTlo[o] = bf16h(x - bf16f(h));
  }
}

// ---------------------------------------------------------------------------
// qout: ddT (A=P, B=Q-rows) -> softmax entirely lane-local (row = cl) ->
// qp registers ARE the B-frag of outT = ctxT * qp^T (16 K=16 MFMAs over j).
// 256 blocks x 1024 thr, wave-independent, zero main-loop barriers.
// LDS: P 64K + swizzled ctxT 64K + ksum 1K = 129 KB, 1 block/CU, 4 waves/SIMD.
// ctxT swizzle: col' = j ^ ((e&15)<<2) -> conflict-free ds_read_b64.
// ---------------------------------------------------------------------------
__global__ __launch_bounds__(1024, 4) void qout_kernel(
    const float* __restrict__ qq, const ushort* __restrict__ P2hi,
    const ushort* __restrict__ P2lo, const float* __restrict__ ksum,
    const ushort* __restrict__ ctxThi, const ushort* __restrict__ ctxTlo,
    float* __restrict__ out) {
  __shared__ __align__(16) ushort PhiL[NFEAT * DHEAD];  // 32 KB
  __shared__ __align__(16) ushort PloL[NFEAT * DHEAD];  // 32 KB
  __shared__ __align__(16) ushort CTh[DHEAD * NFEAT];   // 32 KB (swizzled)
  __shared__ __align__(16) ushort CTl[DHEAD * NFEAT];   // 32 KB (swizzled)
  __shared__ float ksumL[NFEAT];                        // 1 KB
  const int t = threadIdx.x, lane = t & 63, w = t >> 6;
  const int cl = lane & 15, q = lane >> 4;
  const int head = blockIdx.x >> 3, slab = blockIdx.x & 7;
  for (int i = t; i < 2048; i += 1024) {
    ((float4*)PhiL)[i] = ((const float4*)P2hi)[i];
    ((float4*)PloL)[i] = ((const float4*)P2lo)[i];
  }
  {  // stage ctxT with XOR swizzle (4-ushort groups stay contiguous)
    const size_t cb = (size_t)head * DHEAD * NFEAT;
    for (int g = t; g < 4096; g += 1024) {
      int e = g >> 6, j4 = (g & 63) << 2;
      uint2 hv = *(const uint2*)(ctxThi + cb + e * NFEAT + j4);
      uint2 lv = *(const uint2*)(ctxTlo + cb + e * NFEAT + j4);
      int dst = e * NFEAT + (j4 ^ ((e & 15) << 2));
      *(uint2*)&CTh[dst] = hv;
      *(uint2*)&CTl[dst] = lv;
    }
  }
  if (t < NFEAT) ksumL[t] = ksum[head * NFEAT + t];
  __syncthreads();

  for (int s = 0; s < 2; ++s) {
    const int rb = slab * 512 + (w + s * 16) * 16;
    // B-frags: Q rows (col = n = cl), k = d
    const float* xb = qq + ((size_t)(head * NSEQ + rb + cl)) * DHEAD + q * 8;
    float4 pa0 = *(const float4*)(xb);
    float4 pa1 = *(const float4*)(xb + 4);
    float4 pa2 = *(const float4*)(xb + 32);
    float4 pa3 = *(const float4*)(xb + 36);
    float af[2][8] = {{pa0.x, pa0.y, pa0.z, pa0.w, pa1.x, pa1.y, pa1.z, pa1.w},
                      {pa2.x, pa2.y, pa2.z, pa2.w, pa3.x, pa3.y, pa3.z, pa3.w}};
    Frag8 bh[2], bl[2];
    float ssq = 0.f;
#pragma unroll
    for (int ks = 0; ks < 2; ++ks)
#pragma unroll
      for (int i = 0; i < 8; ++i) {
        float x = af[ks][i];
        ssq = fmaf(x, x, ssq);
        ushort h = bf16h(x);
        bh[ks].u[i] = h;
        bl[ks].u[i] = bf16h(x - bf16f(h));
      }
    float s2 = ssq;
    s2 += __shfl_xor(s2, 16);
    s2 += __shfl_xor(s2, 32);  // full ssq of row cl (lane-local diag!)
    // ddT: C: lane(cl,q) = dd[j=jt*16+q*4+r][n=cl]
    v4f acc[16];
#pragma unroll
    for (int jt = 0; jt < 16; ++jt) acc[jt] = (v4f){0.f, 0.f, 0.f, 0.f};
#pragma unroll
    for (int ks = 0; ks < 2; ++ks)
#pragma unroll
      for (int jt = 0; jt < 16; ++jt) {
        const int pidx = ((ks * 4 + q) * NFEAT + jt * 16 + cl) * 8;
        v8s pAh = *(const v8s*)&PhiL[pidx];
        v8s pAl = *(const v8s*)&PloL[pidx];
        acc[jt] = MFMA32(pAh, bh[ks].v, acc[jt]);
        acc[jt] = MFMA32(pAh, bl[ks].v, acc[jt]);
        acc[jt] = MFMA32(pAl, bh[ks].v, acc[jt]);
      }
    // row-max of row cl: in-lane over 64 + across q
    float mr = acc[0][0];
#pragma unroll
    for (int jt = 0; jt < 16; ++jt)
#pragma unroll
      for (int r = 0; r < 4; ++r) mr = fmaxf(mr, acc[jt][r]);
    mr = fmaxf(mr, __shfl_xor(mr, 16));
    mr = fmaxf(mr, __shfl_xor(mr, 32));
    const float mm = mr + DIAG_C * s2;
    // qp + d-partials; qp C-layout == B-frag layout of MFMA16 (k=j=q*4+i)
    float ds = 0.f;
    Frag4 qph[16], qpl[16];
#pragma unroll
    for (int jt = 0; jt < 16; ++jt)
#pragma unroll
      for (int r = 0; r < 4; ++r) {
        float qv = RATIO_C * (__expf(acc[jt][r] - mm) + KEPS_C);
        ds = fmaf(qv, ksumL[jt * 16 + q * 4 + r], ds);
        ushort h = bf16h(qv);
        qph[jt].u[r] = h;
        qpl[jt].u[r] = bf16h(qv - bf16f(h));
      }
    ds += __shfl_xor(ds, 16);
    ds += __shfl_xor(ds, 32);
    const float dinv = 1.0f / ds;
    // outT = ctxT * qp^T: A-frag ctxT[e=et*16+cl][j=jt*16+q*4+i] (swizzled)
    v4f oacc[4];
#pragma unroll
    for (int et = 0; et < 4; ++et) oacc[et] = (v4f){0.f, 0.f, 0.f, 0.f};
#pragma unroll
    for (int et = 0; et < 4; ++et)
#pragma unroll
      for (int jt = 0; jt < 16; ++jt) {
        const int ci = (et * 16 + cl) * NFEAT + ((jt * 16 + q * 4) ^ (cl << 2));
        v4s cth = *(const v4s*)&CTh[ci];
        v4s ctl = *(const v4s*)&CTl[ci];
        oacc[et] = MFMA16(cth, qph[jt].v, oacc[et]);
        oacc[et] = MFMA16(cth, qpl[jt].v, oacc[et]);
        oacc[et] = MFMA16(ctl, qph[jt].v, oacc[et]);
      }
    // C: lane(cl,q) = outT[e=et*16+q*4+r][n=cl] -> float4 store per et
    float* ob = out + ((size_t)(head * NSEQ + rb + cl)) * DHEAD;
#pragma unroll
    for (int et = 0; et < 4; ++et) {
      float4 o;
      o.x = oacc[et][0] * dinv;
      o.y = oacc[et][1] * dinv;
      o.z = oacc[et][2] * dinv;
      o.w = oacc[et][3] * dinv;
      *(float4*)(ob + et * 16 + q * 4) = o;
    }
  }
}

extern "C" void kernel_launch(void* const* d_in, const int* in_sizes, int n_in,
                              void* d_out, int out_size, void* d_ws, size_t ws_size,
                              hipStream_t stream) {
  (void)in_sizes; (void)n_in; (void)out_size; (void)ws_size;
  const float* q = (const float*)d_in[0];
  const float* k = (const float*)d_in[1];
  const float* v = (const float*)d_in[2];
  const float* proj = (const float*)d_in[3];
  float* out = (float*)d_out;
  unsigned char* ws = (unsigned char*)d_ws;
  unsigned* kmax_u = (unsigned*)ws;                    // @0
  float* ksum = (float*)(ws + 256);                    // 32 KB
  float* ctx = (float*)(ws + 33024);                   // 2 MB
  ushort* P2hi = (ushort*)(ws + 2130176);              // 32 KB
  ushort* P2lo = (ushort*)(ws + 2162944);              // 32 KB
  ushort* ctxThi = (ushort*)(ws + 2195712);            // 1 MB
  ushort* ctxTlo = (ushort*)(ws + 3244288);            // 1 MB -> end 4292864
  (void)hipMemsetAsync(d_ws, 0, 2130176, stream);  // kmax_u + ksum + ctx
  hipLaunchKernelGGL(prep_kernel, dim3(64), dim3(256), 0, stream, proj, P2hi, P2lo);
  hipLaunchKernelGGL(kmax_kernel, dim3(256), dim3(1024), 0, stream, k, P2hi,
                     kmax_u);
  hipLaunchKernelGGL(kctx_kernel, dim3(256), dim3(1024), 0, stream, k, v, P2hi,
                     P2lo, kmax_u, ksum, ctx);
  hipLaunchKernelGGL(ctxprep_kernel, dim3(128), dim3(256), 0, stream, ctx,
                     ctxThi, ctxTlo);
  hipLaunchKernelGGL(qout_kernel, dim3(256), dim3(1024), 0, stream, q, P2hi,
                     P2lo, ksum, ctxThi, ctxTlo, out);
}

// Round 5
// 511.493 us; speedup vs baseline: 1.5610x; 1.5610x over previous
//
#include <hip/hip_runtime.h>

#define NFEAT 256
#define DHEAD 64
#define NSEQ  4096

constexpr float NORM_C  = 0.35355339059327373f;  // 64^-0.25
constexpr float RATIO_C = 0.0625f;               // 256^-0.5
constexpr float DIAG_C  = 0.0625f;               // 0.5 * 64^-0.5
constexpr float KEPS_C  = 1e-4f;

using v8s = __attribute__((ext_vector_type(8))) short;
using v4s = __attribute__((ext_vector_type(4))) short;
using v4f = __attribute__((ext_vector_type(4))) float;
union Frag8 { v8s v; ushort u[8]; };
union Frag4 { v4s v; ushort u[4]; };

__device__ __forceinline__ ushort bf16h(float x) {
  unsigned u = __float_as_uint(x);
  return (ushort)((u + 0x7FFFu + ((u >> 16) & 1)) >> 16);
}
__device__ __forceinline__ float bf16f(ushort h) {
  return __uint_as_float(((unsigned)h) << 16);
}
__device__ __forceinline__ unsigned enc_f(float f) {
  unsigned u = __float_as_uint(f);
  return (u & 0x80000000u) ? ~u : (u | 0x80000000u);
}
__device__ __forceinline__ float dec_f(unsigned e) {
  return (e & 0x80000000u) ? __uint_as_float(e ^ 0x80000000u) : __uint_as_float(~e);
}

#define MFMA32(a, b, c) __builtin_amdgcn_mfma_f32_16x16x32_bf16((a), (b), (c), 0, 0, 0)
// gfx90a+/gfx950 K=16 bf16 MFMA; __has_builtin unreliable in host pass.
#if defined(__HIP_DEVICE_COMPILE__)
#define MFMA16(a, b, c) __builtin_amdgcn_mfma_f32_16x16x16bf16_1k((a), (b), (c), 0, 0, 0)
#else
#define MFMA16(a, b, c) (c)
#endif

// P (NORM folded) -> bf16 hi/lo planes, FRAGMENT-MAJOR:
//   P2[(d>>3)*256*8 + j*8 + (d&7)]
__global__ void prep_kernel(const float* __restrict__ proj,
                            ushort* __restrict__ P2hi, ushort* __restrict__ P2lo) {
  int i = blockIdx.x * 256 + threadIdx.x;
  if (i < NFEAT * DHEAD) {
    int j = i >> 6, d = i & 63;
    float x = NORM_C * proj[i];
    ushort h = bf16h(x);
    int off = ((d >> 3) * NFEAT + j) * 8 + (d & 7);
    P2hi[off] = h;
    P2lo[off] = bf16h(x - bf16f(h));
  }
}

// ---------------------------------------------------------------------------
// kmax (round-2 version, verbatim — passed twice): global max of dd_k via
// MFMA, SINGLE bf16 plane. 512 blocks x 512 thr, LDS 32 KB, 2 blocks/CU.
// ---------------------------------------------------------------------------
__global__ __launch_bounds__(512, 4) void kmax_kernel(
    const float* __restrict__ kk, const ushort* __restrict__ P2hi,
    unsigned* __restrict__ kmax_u) {
  __shared__ __align__(16) ushort PhiL[NFEAT * DHEAD];  // 32 KB
  __shared__ float wred[8];
  const int t = threadIdx.x, lane = t & 63, w = t >> 6;
  const int cl = lane & 15, q = lane >> 4;
  const int mw = w & 1, jq = w >> 1;
  const int head = blockIdx.x >> 4, slab = blockIdx.x & 15;
  for (int i = t; i < 2048; i += 512)
    ((float4*)PhiL)[i] = ((const float4*)P2hi)[i];
  const float* abase =
      kk + ((size_t)(head * NSEQ + slab * 256 + mw * 16 + cl)) * DHEAD + q * 8;
  float4 pa0 = *(const float4*)(abase);
  float4 pa1 = *(const float4*)(abase + 4);
  float4 pa2 = *(const float4*)(abase + 32);
  float4 pa3 = *(const float4*)(abase + 36);
  __syncthreads();
  float mx = -3.0e38f;
  for (int c = 0; c < 8; ++c) {
    float af[2][8] = {{pa0.x, pa0.y, pa0.z, pa0.w, pa1.x, pa1.y, pa1.z, pa1.w},
                      {pa2.x, pa2.y, pa2.z, pa2.w, pa3.x, pa3.y, pa3.z, pa3.w}};
    Frag8 ah[2];
#pragma unroll
    for (int ks = 0; ks < 2; ++ks)
#pragma unroll
      for (int i = 0; i < 8; ++i) ah[ks].u[i] = bf16h(af[ks][i]);
    if (c < 7) {
      const float* nx = abase + (size_t)(c + 1) * 32 * DHEAD;
      pa0 = *(const float4*)(nx);
      pa1 = *(const float4*)(nx + 4);
      pa2 = *(const float4*)(nx + 32);
      pa3 = *(const float4*)(nx + 36);
    }
    v4f acc[4];
#pragma unroll
    for (int jt = 0; jt < 4; ++jt) acc[jt] = (v4f){0.f, 0.f, 0.f, 0.f};
#pragma unroll
    for (int ks = 0; ks < 2; ++ks)
#pragma unroll
      for (int jt = 0; jt < 4; ++jt) {
        v8s bh = *(const v8s*)&PhiL[((ks * 4 + q) * NFEAT + jq * 64 + jt * 16 + cl) * 8];
        acc[jt] = MFMA32(ah[ks].v, bh, acc[jt]);
      }
#pragma unroll
    for (int jt = 0; jt < 4; ++jt)
#pragma unroll
      for (int r = 0; r < 4; ++r) mx = fmaxf(mx, acc[jt][r]);
  }
  for (int s = 1; s < 64; s <<= 1) mx = fmaxf(mx, __shfl_xor(mx, s));
  if (lane == 0) wred[w] = mx;
  __syncthreads();
  if (t == 0) {
    float r = wred[0];
#pragma unroll
    for (int i = 1; i < 8; ++i) r = fmaxf(r, wred[i]);
    atomicMax(kmax_u, enc_f(r));
  }
}

// ---------------------------------------------------------------------------
// kctx: barrier-free transpose-trick (math hw-verified in round 4), now at
// 512 thr, __launch_bounds__(512,2) -> 256-reg budget, NO spill.
// 8 waves = (jq = w&3 j-quarter) x (rg = w>>2 row-interleave of 2);
// 16 steps of 16 rows. kp streamed per jt (only one tile live).
// LDS = P both planes (64 KB). V frags preloaded per step (L1/L2 reuse
// across the 4 jq waves sharing rows).
// ---------------------------------------------------------------------------
__global__ __launch_bounds__(512, 2) void kctx_kernel(
    const float* __restrict__ kk, const float* __restrict__ vv,
    const ushort* __restrict__ P2hi, const ushort* __restrict__ P2lo,
    const unsigned* __restrict__ kmax_u, float* __restrict__ ksum,
    float* __restrict__ ctx) {
  __shared__ __align__(16) ushort PhiL[NFEAT * DHEAD];  // 32 KB
  __shared__ __align__(16) ushort PloL[NFEAT * DHEAD];  // 32 KB
  const int t = threadIdx.x, lane = t & 63, w = t >> 6;
  const int cl = lane & 15, q = lane >> 4;
  const int jq = w & 3, rg = w >> 2;
  const int head = blockIdx.x >> 3, slab = blockIdx.x & 7;
  const float m = dec_f(*kmax_u);
  for (int i = t; i < 2048; i += 512) {
    ((float4*)PhiL)[i] = ((const float4*)P2hi)[i];
    ((float4*)PloL)[i] = ((const float4*)P2lo)[i];
  }
  __syncthreads();
  float ksacc[4] = {0.f, 0.f, 0.f, 0.f};
  v4f ctxacc[4][4];  // [jt][et]
#pragma unroll
  for (int jt = 0; jt < 4; ++jt)
#pragma unroll
    for (int et = 0; et < 4; ++et) ctxacc[jt][et] = (v4f){0.f, 0.f, 0.f, 0.f};

  for (int cc = 0; cc < 16; ++cc) {
    const int rb = slab * 512 + (cc * 2 + rg) * 16;
    // K rows: A-frags (row = cl, k = d)
    const float* xb = kk + ((size_t)(head * NSEQ + rb + cl)) * DHEAD + q * 8;
    float4 pa0 = *(const float4*)(xb);
    float4 pa1 = *(const float4*)(xb + 4);
    float4 pa2 = *(const float4*)(xb + 32);
    float4 pa3 = *(const float4*)(xb + 36);
    float af[2][8] = {{pa0.x, pa0.y, pa0.z, pa0.w, pa1.x, pa1.y, pa1.z, pa1.w},
                      {pa2.x, pa2.y, pa2.z, pa2.w, pa3.x, pa3.y, pa3.z, pa3.w}};
    Frag8 ah[2], al[2];
    float ssq = 0.f;
#pragma unroll
    for (int ks = 0; ks < 2; ++ks)
#pragma unroll
      for (int i = 0; i < 8; ++i) {
        float x = af[ks][i];
        ssq = fmaf(x, x, ssq);
        ushort h = bf16h(x);
        ah[ks].u[i] = h;
        al[ks].u[i] = bf16h(x - bf16f(h));
      }
    float s2 = ssq;
    s2 += __shfl_xor(s2, 16);
    s2 += __shfl_xor(s2, 32);  // full ssq of row cl at every lane
    float dg[4];
#pragma unroll
    for (int r = 0; r < 4; ++r) dg[r] = DIAG_C * __shfl(s2, q * 4 + r);
    // V B-frags for this step: V[rb + q*4+i][et*16+cl]
    Frag4 bvh[4], bvl[4];
    {
      const float* vb = vv + ((size_t)(head * NSEQ + rb + q * 4)) * DHEAD + cl;
#pragma unroll
      for (int et = 0; et < 4; ++et)
#pragma unroll
        for (int i = 0; i < 4; ++i) {
          float x = vb[(size_t)i * DHEAD + et * 16];
          ushort h = bf16h(x);
          bvh[et].u[i] = h;
          bvl[et].u[i] = bf16h(x - bf16f(h));
        }
    }
    // stream jt: dd -> kp (one tile live) -> MFMA16 into ctxacc
#pragma unroll
    for (int jt = 0; jt < 4; ++jt) {
      v4f acc = (v4f){0.f, 0.f, 0.f, 0.f};
#pragma unroll
      for (int ks = 0; ks < 2; ++ks) {
        const int pidx = ((ks * 4 + q) * NFEAT + jq * 64 + jt * 16 + cl) * 8;
        v8s bh = *(const v8s*)&PhiL[pidx];
        v8s bl = *(const v8s*)&PloL[pidx];
        acc = MFMA32(ah[ks].v, bh, acc);
        acc = MFMA32(ah[ks].v, bl, acc);
        acc = MFMA32(al[ks].v, bh, acc);
      }
      Frag4 kph, kpl;
#pragma unroll
      for (int r = 0; r < 4; ++r) {
        float e_ = RATIO_C * (__expf(acc[r] - dg[r] - m) + KEPS_C);
        ksacc[jt] += e_;
        ushort h = bf16h(e_);
        kph.u[r] = h;
        kpl.u[r] = bf16h(e_ - bf16f(h));
      }
#pragma unroll
      for (int et = 0; et < 4; ++et) {
        ctxacc[jt][et] = MFMA16(kph.v, bvh[et].v, ctxacc[jt][et]);
        ctxacc[jt][et] = MFMA16(kph.v, bvl[et].v, ctxacc[jt][et]);
        ctxacc[jt][et] = MFMA16(kpl.v, bvh[et].v, ctxacc[jt][et]);
      }
    }
  }
#pragma unroll
  for (int jt = 0; jt < 4; ++jt) {
    float s = ksacc[jt];
    s += __shfl_xor(s, 16);
    s += __shfl_xor(s, 32);
    if (q == 0) atomicAdd(&ksum[head * NFEAT + jq * 64 + jt * 16 + cl], s);
  }
#pragma unroll
  for (int jt = 0; jt < 4; ++jt)
#pragma unroll
    for (int et = 0; et < 4; ++et)
#pragma unroll
      for (int r = 0; r < 4; ++r) {
        int j = jq * 64 + jt * 16 + q * 4 + r;
        int e = et * 16 + cl;
        atomicAdd(&ctx[((size_t)head * NFEAT + j) * DHEAD + e],
                  ctxacc[jt][et][r]);
      }
}

// ---------------------------------------------------------------------------
// ctxprep: ctx fp32 [h][j][e] -> ctxT bf16 hi/lo planes [h][e][j]
// ---------------------------------------------------------------------------
__global__ void ctxprep_kernel(const float* __restrict__ ctx,
                               ushort* __restrict__ ctxThi,
                               ushort* __restrict__ ctxTlo) {
  __shared__ float tile[64 * 65];
  const int head = blockIdx.x >> 2, jb = blockIdx.x & 3, t = threadIdx.x;
#pragma unroll
  for (int i = 0; i < 16; ++i) {
    int idx = t + i * 256;
    int jj = idx >> 6, e = idx & 63;
    tile[jj * 65 + e] = ctx[((size_t)head * NFEAT + jb * 64 + jj) * DHEAD + e];
  }
  __syncthreads();
#pragma unroll
  for (int i = 0; i < 16; ++i) {
    int idx = t + i * 256;
    int e = idx >> 6, jj = idx & 63;
    float x = tile[jj * 65 + e];
    ushort h = bf16h(x);
    size_t o = ((size_t)head * DHEAD + e) * NFEAT + jb * 64 + jj;
    ctxThi[o] = h;
    ctxTlo[o] = bf16h(x - bf16f(h));
  }
}

// ---------------------------------------------------------------------------
// qout: barrier-free transpose-trick (math hw-verified in round 4), now at
// 512 thr, __launch_bounds__(512,2) -> 256-reg budget so acc[16]+qp[16]
// (~180 live regs) fit WITHOUT spill. 8 waves x 4 steps of 16 rows.
// LDS: P 64K + swizzled ctxT 64K + ksum 1K = 129 KB (1 block/CU; grid=1/CU
// anyway). Zero main-loop barriers.
// ---------------------------------------------------------------------------
__global__ __launch_bounds__(512, 2) void qout_kernel(
    const float* __restrict__ qq, const ushort* __restrict__ P2hi,
    const ushort* __restrict__ P2lo, const float* __restrict__ ksum,
    const ushort* __restrict__ ctxThi, const ushort* __restrict__ ctxTlo,
    float* __restrict__ out) {
  __shared__ __align__(16) ushort PhiL[NFEAT * DHEAD];  // 32 KB
  __shared__ __align__(16) ushort PloL[NFEAT * DHEAD];  // 32 KB
  __shared__ __align__(16) ushort CTh[DHEAD * NFEAT];   // 32 KB (swizzled)
  __shared__ __align__(16) ushort CTl[DHEAD * NFEAT];   // 32 KB (swizzled)
  __shared__ float ksumL[NFEAT];                        // 1 KB
  const int t = threadIdx.x, lane = t & 63, w = t >> 6;
  const int cl = lane & 15, q = lane >> 4;
  const int head = blockIdx.x >> 3, slab = blockIdx.x & 7;
  for (int i = t; i < 2048; i += 512) {
    ((float4*)PhiL)[i] = ((const float4*)P2hi)[i];
    ((float4*)PloL)[i] = ((const float4*)P2lo)[i];
  }
  {  // stage ctxT with XOR swizzle (4-ushort groups stay contiguous)
    const size_t cb = (size_t)head * DHEAD * NFEAT;
    for (int g = t; g < 4096; g += 512) {
      int e = g >> 6, j4 = (g & 63) << 2;
      uint2 hv = *(const uint2*)(ctxThi + cb + e * NFEAT + j4);
      uint2 lv = *(const uint2*)(ctxTlo + cb + e * NFEAT + j4);
      int dst = e * NFEAT + (j4 ^ ((e & 15) << 2));
      *(uint2*)&CTh[dst] = hv;
      *(uint2*)&CTl[dst] = lv;
    }
  }
  if (t < NFEAT) ksumL[t] = ksum[head * NFEAT + t];
  __syncthreads();

  for (int s = 0; s < 4; ++s) {
    const int rb = slab * 512 + (w + s * 8) * 16;
    // B-frags: Q rows (col = n = cl), k = d
    const float* xb = qq + ((size_t)(head * NSEQ + rb + cl)) * DHEAD + q * 8;
    float4 pa0 = *(const float4*)(xb);
    float4 pa1 = *(const float4*)(xb + 4);
    float4 pa2 = *(const float4*)(xb + 32);
    float4 pa3 = *(const float4*)(xb + 36);
    float af[2][8] = {{pa0.x, pa0.y, pa0.z, pa0.w, pa1.x, pa1.y, pa1.z, pa1.w},
                      {pa2.x, pa2.y, pa2.z, pa2.w, pa3.x, pa3.y, pa3.z, pa3.w}};
    Frag8 bh[2], bl[2];
    float ssq = 0.f;
#pragma unroll
    for (int ks = 0; ks < 2; ++ks)
#pragma unroll
      for (int i = 0; i < 8; ++i) {
        float x = af[ks][i];
        ssq = fmaf(x, x, ssq);
        ushort h = bf16h(x);
        bh[ks].u[i] = h;
        bl[ks].u[i] = bf16h(x - bf16f(h));
      }
    float s2 = ssq;
    s2 += __shfl_xor(s2, 16);
    s2 += __shfl_xor(s2, 32);  // full ssq of row cl (lane-local diag)
    // ddT: C: lane(cl,q) = dd[j=jt*16+q*4+r][n=cl]
    v4f acc[16];
#pragma unroll
    for (int jt = 0; jt < 16; ++jt) acc[jt] = (v4f){0.f, 0.f, 0.f, 0.f};
#pragma unroll
    for (int ks = 0; ks < 2; ++ks)
#pragma unroll
      for (int jt = 0; jt < 16; ++jt) {
        const int pidx = ((ks * 4 + q) * NFEAT + jt * 16 + cl) * 8;
        v8s pAh = *(const v8s*)&PhiL[pidx];
        v8s pAl = *(const v8s*)&PloL[pidx];
        acc[jt] = MFMA32(pAh, bh[ks].v, acc[jt]);
        acc[jt] = MFMA32(pAh, bl[ks].v, acc[jt]);
        acc[jt] = MFMA32(pAl, bh[ks].v, acc[jt]);
      }
    // row-max of row cl
    float mr = acc[0][0];
#pragma unroll
    for (int jt = 0; jt < 16; ++jt)
#pragma unroll
      for (int r = 0; r < 4; ++r) mr = fmaxf(mr, acc[jt][r]);
    mr = fmaxf(mr, __shfl_xor(mr, 16));
    mr = fmaxf(mr, __shfl_xor(mr, 32));
    const float mm = mr + DIAG_C * s2;
    // qp + d; qp C-layout == B-frag layout of MFMA16 (k=j=q*4+i)
    float ds = 0.f;
    Frag4 qph[16], qpl[16];
#pragma unroll
    for (int jt = 0; jt < 16; ++jt)
#pragma unroll
      for (int r = 0; r < 4; ++r) {
        float qv = RATIO_C * (__expf(acc[jt][r] - mm) + KEPS_C);
        ds = fmaf(qv, ksumL[jt * 16 + q * 4 + r], ds);
        ushort h = bf16h(qv);
        qph[jt].u[r] = h;
        qpl[jt].u[r] = bf16h(qv - bf16f(h));
      }
    ds += __shfl_xor(ds, 16);
    ds += __shfl_xor(ds, 32);
    const float dinv = 1.0f / ds;
    // outT = ctxT * qp^T: A-frag ctxT[e=et*16+cl][j=jt*16+q*4+i] (swizzled)
    v4f oacc[4];
#pragma unroll
    for (int et = 0; et < 4; ++et) oacc[et] = (v4f){0.f, 0.f, 0.f, 0.f};
#pragma unroll
    for (int et = 0; et < 4; ++et)
#pragma unroll
      for (int jt = 0; jt < 16; ++jt) {
        const int ci = (et * 16 + cl) * NFEAT + ((jt * 16 + q * 4) ^ (cl << 2));
        v4s cth = *(const v4s*)&CTh[ci];
        v4s ctl = *(const v4s*)&CTl[ci];
        oacc[et] = MFMA16(cth, qph[jt].v, oacc[et]);
        oacc[et] = MFMA16(cth, qpl[jt].v, oacc[et]);
        oacc[et] = MFMA16(ctl, qph[jt].v, oacc[et]);
      }
    // C: lane(cl,q) = outT[e=et*16+q*4+r][n=cl] -> float4 store per et
    float* ob = out + ((size_t)(head * NSEQ + rb + cl)) * DHEAD;
#pragma unroll
    for (int et = 0; et < 4; ++et) {
      float4 o;
      o.x = oacc[et][0] * dinv;
      o.y = oacc[et][1] * dinv;
      o.z = oacc[et][2] * dinv;
      o.w = oacc[et][3] * dinv;
      *(float4*)(ob + et * 16 + q * 4) = o;
    }
  }
}

extern "C" void kernel_launch(void* const* d_in, const int* in_sizes, int n_in,
                              void* d_out, int out_size, void* d_ws, size_t ws_size,
                              hipStream_t stream) {
  (void)in_sizes; (void)n_in; (void)out_size; (void)ws_size;
  const float* q = (const float*)d_in[0];
  const float* k = (const float*)d_in[1];
  const float* v = (const float*)d_in[2];
  const float* proj = (const float*)d_in[3];
  float* out = (float*)d_out;
  unsigned char* ws = (unsigned char*)d_ws;
  unsigned* kmax_u = (unsigned*)ws;                    // @0
  float* ksum = (float*)(ws + 256);                    // 32 KB
  float* ctx = (float*)(ws + 33024);                   // 2 MB
  ushort* P2hi = (ushort*)(ws + 2130176);              // 32 KB
  ushort* P2lo = (ushort*)(ws + 2162944);              // 32 KB
  ushort* ctxThi = (ushort*)(ws + 2195712);            // 1 MB
  ushort* ctxTlo = (ushort*)(ws + 3244288);            // 1 MB -> end 4292864
  (void)hipMemsetAsync(d_ws, 0, 2130176, stream);  // kmax_u + ksum + ctx
  hipLaunchKernelGGL(prep_kernel, dim3(64), dim3(256), 0, stream, proj, P2hi, P2lo);
  hipLaunchKernelGGL(kmax_kernel, dim3(512), dim3(512), 0, stream, k, P2hi,
                     kmax_u);
  hipLaunchKernelGGL(kctx_kernel, dim3(256), dim3(512), 0, stream, k, v, P2hi,
                     P2lo, kmax_u, ksum, ctx);
  hipLaunchKernelGGL(ctxprep_kernel, dim3(128), dim3(256), 0, stream, ctx,
                     ctxThi, ctxTlo);
  hipLaunchKernelGGL(qout_kernel, dim3(256), dim3(512), 0, stream, q, P2hi,
                     P2lo, ksum, ctxThi, ctxTlo, out);
}

// Round 6
// 480.960 us; speedup vs baseline: 1.6601x; 1.0635x over previous
//
#include <hip/hip_runtime.h>

#define NFEAT 256
#define DHEAD 64
#define NSEQ  4096

constexpr float NORM_C  = 0.35355339059327373f;  // 64^-0.25
constexpr float RATIO_C = 0.0625f;               // 256^-0.5
constexpr float DIAG_C  = 0.0625f;               // 0.5 * 64^-0.5
constexpr float KEPS_C  = 1e-4f;

using v8s = __attribute__((ext_vector_type(8))) short;
using v4s = __attribute__((ext_vector_type(4))) short;
using v4f = __attribute__((ext_vector_type(4))) float;
union Frag8 { v8s v; ushort u[8]; };
union Frag4 { v4s v; ushort u[4]; };

__device__ __forceinline__ ushort bf16h(float x) {
  unsigned u = __float_as_uint(x);
  return (ushort)((u + 0x7FFFu + ((u >> 16) & 1)) >> 16);
}
__device__ __forceinline__ float bf16f(ushort h) {
  return __uint_as_float(((unsigned)h) << 16);
}
__device__ __forceinline__ unsigned enc_f(float f) {
  unsigned u = __float_as_uint(f);
  return (u & 0x80000000u) ? ~u : (u | 0x80000000u);
}
__device__ __forceinline__ float dec_f(unsigned e) {
  return (e & 0x80000000u) ? __uint_as_float(e ^ 0x80000000u) : __uint_as_float(~e);
}

#define MFMA32(a, b, c) __builtin_amdgcn_mfma_f32_16x16x32_bf16((a), (b), (c), 0, 0, 0)
// gfx90a+/gfx950 K=16 bf16 MFMA; __has_builtin unreliable in host pass.
#if defined(__HIP_DEVICE_COMPILE__)
#define MFMA16(a, b, c) __builtin_amdgcn_mfma_f32_16x16x16bf16_1k((a), (b), (c), 0, 0, 0)
#else
#define MFMA16(a, b, c) (c)
#endif

// P (NORM folded) -> bf16 hi/lo planes, FRAGMENT-MAJOR:
//   P2[(d>>3)*256*8 + j*8 + (d&7)]
__global__ void prep_kernel(const float* __restrict__ proj,
                            ushort* __restrict__ P2hi, ushort* __restrict__ P2lo) {
  int i = blockIdx.x * 256 + threadIdx.x;
  if (i < NFEAT * DHEAD) {
    int j = i >> 6, d = i & 63;
    float x = NORM_C * proj[i];
    ushort h = bf16h(x);
    int off = ((d >> 3) * NFEAT + j) * 8 + (d & 7);
    P2hi[off] = h;
    P2lo[off] = bf16h(x - bf16f(h));
  }
}

// ---------------------------------------------------------------------------
// kmax (unchanged, passed 3x): global max of dd_k via MFMA, single bf16
// plane. 512 blocks x 512 thr, LDS 32 KB, 2 blocks/CU.
// ---------------------------------------------------------------------------
__global__ __launch_bounds__(512, 4) void kmax_kernel(
    const float* __restrict__ kk, const ushort* __restrict__ P2hi,
    unsigned* __restrict__ kmax_u) {
  __shared__ __align__(16) ushort PhiL[NFEAT * DHEAD];  // 32 KB
  __shared__ float wred[8];
  const int t = threadIdx.x, lane = t & 63, w = t >> 6;
  const int cl = lane & 15, q = lane >> 4;
  const int mw = w & 1, jq = w >> 1;
  const int head = blockIdx.x >> 4, slab = blockIdx.x & 15;
  for (int i = t; i < 2048; i += 512)
    ((float4*)PhiL)[i] = ((const float4*)P2hi)[i];
  const float* abase =
      kk + ((size_t)(head * NSEQ + slab * 256 + mw * 16 + cl)) * DHEAD + q * 8;
  float4 pa0 = *(const float4*)(abase);
  float4 pa1 = *(const float4*)(abase + 4);
  float4 pa2 = *(const float4*)(abase + 32);
  float4 pa3 = *(const float4*)(abase + 36);
  __syncthreads();
  float mx = -3.0e38f;
  for (int c = 0; c < 8; ++c) {
    float af[2][8] = {{pa0.x, pa0.y, pa0.z, pa0.w, pa1.x, pa1.y, pa1.z, pa1.w},
                      {pa2.x, pa2.y, pa2.z, pa2.w, pa3.x, pa3.y, pa3.z, pa3.w}};
    Frag8 ah[2];
#pragma unroll
    for (int ks = 0; ks < 2; ++ks)
#pragma unroll
      for (int i = 0; i < 8; ++i) ah[ks].u[i] = bf16h(af[ks][i]);
    if (c < 7) {
      const float* nx = abase + (size_t)(c + 1) * 32 * DHEAD;
      pa0 = *(const float4*)(nx);
      pa1 = *(const float4*)(nx + 4);
      pa2 = *(const float4*)(nx + 32);
      pa3 = *(const float4*)(nx + 36);
    }
    v4f acc[4];
#pragma unroll
    for (int jt = 0; jt < 4; ++jt) acc[jt] = (v4f){0.f, 0.f, 0.f, 0.f};
#pragma unroll
    for (int ks = 0; ks < 2; ++ks)
#pragma unroll
      for (int jt = 0; jt < 4; ++jt) {
        v8s bh = *(const v8s*)&PhiL[((ks * 4 + q) * NFEAT + jq * 64 + jt * 16 + cl) * 8];
        acc[jt] = MFMA32(ah[ks].v, bh, acc[jt]);
      }
#pragma unroll
    for (int jt = 0; jt < 4; ++jt)
#pragma unroll
      for (int r = 0; r < 4; ++r) mx = fmaxf(mx, acc[jt][r]);
  }
  for (int s = 1; s < 64; s <<= 1) mx = fmaxf(mx, __shfl_xor(mx, s));
  if (lane == 0) wred[w] = mx;
  __syncthreads();
  if (t == 0) {
    float r = wred[0];
#pragma unroll
    for (int i = 1; i < 8; ++i) r = fmaxf(r, wred[i]);
    atomicMax(kmax_u, enc_f(r));
  }
}

// ---------------------------------------------------------------------------
// kctx: barrier-free transpose-trick (hw-verified), 512 thr, (512,2).
// NEW: next-step K/V register prefetch so the 16 strided V dword loads and
// 4 K float4 loads hide under the current step's MFMA/exp work.
// ---------------------------------------------------------------------------
__global__ __launch_bounds__(512, 2) void kctx_kernel(
    const float* __restrict__ kk, const float* __restrict__ vv,
    const ushort* __restrict__ P2hi, const ushort* __restrict__ P2lo,
    const unsigned* __restrict__ kmax_u, float* __restrict__ ksum,
    float* __restrict__ ctx) {
  __shared__ __align__(16) ushort PhiL[NFEAT * DHEAD];  // 32 KB
  __shared__ __align__(16) ushort PloL[NFEAT * DHEAD];  // 32 KB
  const int t = threadIdx.x, lane = t & 63, w = t >> 6;
  const int cl = lane & 15, q = lane >> 4;
  const int jq = w & 3, rg = w >> 2;
  const int head = blockIdx.x >> 3, slab = blockIdx.x & 7;
  const float m = dec_f(*kmax_u);
  for (int i = t; i < 2048; i += 512) {
    ((float4*)PhiL)[i] = ((const float4*)P2hi)[i];
    ((float4*)PloL)[i] = ((const float4*)P2lo)[i];
  }
  __syncthreads();
  float ksacc[4] = {0.f, 0.f, 0.f, 0.f};
  v4f ctxacc[4][4];  // [jt][et]
#pragma unroll
  for (int jt = 0; jt < 4; ++jt)
#pragma unroll
    for (int et = 0; et < 4; ++et) ctxacc[jt][et] = (v4f){0.f, 0.f, 0.f, 0.f};

  const float* abase =
      kk + ((size_t)(head * NSEQ + slab * 512 + rg * 16 + cl)) * DHEAD + q * 8;
  const float* vbase =
      vv + ((size_t)(head * NSEQ + slab * 512 + rg * 16 + q * 4)) * DHEAD + cl;
  float4 pa0 = *(const float4*)(abase);
  float4 pa1 = *(const float4*)(abase + 4);
  float4 pa2 = *(const float4*)(abase + 32);
  float4 pa3 = *(const float4*)(abase + 36);
  float vr[16];
#pragma unroll
  for (int u = 0; u < 16; ++u) vr[u] = vbase[(u & 3) * DHEAD + (u >> 2) * 16];

  for (int cc = 0; cc < 16; ++cc) {
    const int rb = slab * 512 + (cc * 2 + rg) * 16;
    float af[2][8] = {{pa0.x, pa0.y, pa0.z, pa0.w, pa1.x, pa1.y, pa1.z, pa1.w},
                      {pa2.x, pa2.y, pa2.z, pa2.w, pa3.x, pa3.y, pa3.z, pa3.w}};
    Frag8 ah[2], al[2];
    float ssq = 0.f;
#pragma unroll
    for (int ks = 0; ks < 2; ++ks)
#pragma unroll
      for (int i = 0; i < 8; ++i) {
        float x = af[ks][i];
        ssq = fmaf(x, x, ssq);
        ushort h = bf16h(x);
        ah[ks].u[i] = h;
        al[ks].u[i] = bf16h(x - bf16f(h));
      }
    Frag4 bvh[4], bvl[4];
#pragma unroll
    for (int et = 0; et < 4; ++et)
#pragma unroll
      for (int i = 0; i < 4; ++i) {
        float x = vr[et * 4 + i];
        ushort h = bf16h(x);
        bvh[et].u[i] = h;
        bvl[et].u[i] = bf16h(x - bf16f(h));
      }
    if (cc < 15) {  // prefetch next step's K and V into registers
      const float* nx = abase + (size_t)(cc + 1) * 32 * DHEAD;
      pa0 = *(const float4*)(nx);
      pa1 = *(const float4*)(nx + 4);
      pa2 = *(const float4*)(nx + 32);
      pa3 = *(const float4*)(nx + 36);
      const float* nv = vbase + (size_t)(cc + 1) * 32 * DHEAD;
#pragma unroll
      for (int u = 0; u < 16; ++u) vr[u] = nv[(u & 3) * DHEAD + (u >> 2) * 16];
    }
    float s2 = ssq;
    s2 += __shfl_xor(s2, 16);
    s2 += __shfl_xor(s2, 32);  // full ssq of row cl at every lane
    float dg[4];
#pragma unroll
    for (int r = 0; r < 4; ++r) dg[r] = DIAG_C * __shfl(s2, q * 4 + r);
    // stream jt: dd -> kp (one tile live) -> MFMA16 into ctxacc
#pragma unroll
    for (int jt = 0; jt < 4; ++jt) {
      v4f acc = (v4f){0.f, 0.f, 0.f, 0.f};
#pragma unroll
      for (int ks = 0; ks < 2; ++ks) {
        const int pidx = ((ks * 4 + q) * NFEAT + jq * 64 + jt * 16 + cl) * 8;
        v8s bh = *(const v8s*)&PhiL[pidx];
        v8s bl = *(const v8s*)&PloL[pidx];
        acc = MFMA32(ah[ks].v, bh, acc);
        acc = MFMA32(ah[ks].v, bl, acc);
        acc = MFMA32(al[ks].v, bh, acc);
      }
      Frag4 kph, kpl;
#pragma unroll
      for (int r = 0; r < 4; ++r) {
        float e_ = RATIO_C * (__expf(acc[r] - dg[r] - m) + KEPS_C);
        ksacc[jt] += e_;
        ushort h = bf16h(e_);
        kph.u[r] = h;
        kpl.u[r] = bf16h(e_ - bf16f(h));
      }
#pragma unroll
      for (int et = 0; et < 4; ++et) {
        ctxacc[jt][et] = MFMA16(kph.v, bvh[et].v, ctxacc[jt][et]);
        ctxacc[jt][et] = MFMA16(kph.v, bvl[et].v, ctxacc[jt][et]);
        ctxacc[jt][et] = MFMA16(kpl.v, bvh[et].v, ctxacc[jt][et]);
      }
    }
    (void)rb;
  }
#pragma unroll
  for (int jt = 0; jt < 4; ++jt) {
    float s = ksacc[jt];
    s += __shfl_xor(s, 16);
    s += __shfl_xor(s, 32);
    if (q == 0) atomicAdd(&ksum[head * NFEAT + jq * 64 + jt * 16 + cl], s);
  }
#pragma unroll
  for (int jt = 0; jt < 4; ++jt)
#pragma unroll
    for (int et = 0; et < 4; ++et)
#pragma unroll
      for (int r = 0; r < 4; ++r) {
        int j = jq * 64 + jt * 16 + q * 4 + r;
        int e = et * 16 + cl;
        atomicAdd(&ctx[((size_t)head * NFEAT + j) * DHEAD + e],
                  ctxacc[jt][et][r]);
      }
}

// ---------------------------------------------------------------------------
// ctxprep: ctx fp32 [h][j][e] -> ctxT bf16 hi/lo planes [h][e][j]
// ---------------------------------------------------------------------------
__global__ void ctxprep_kernel(const float* __restrict__ ctx,
                               ushort* __restrict__ ctxThi,
                               ushort* __restrict__ ctxTlo) {
  __shared__ float tile[64 * 65];
  const int head = blockIdx.x >> 2, jb = blockIdx.x & 3, t = threadIdx.x;
#pragma unroll
  for (int i = 0; i < 16; ++i) {
    int idx = t + i * 256;
    int jj = idx >> 6, e = idx & 63;
    tile[jj * 65 + e] = ctx[((size_t)head * NFEAT + jb * 64 + jj) * DHEAD + e];
  }
  __syncthreads();
#pragma unroll
  for (int i = 0; i < 16; ++i) {
    int idx = t + i * 256;
    int e = idx >> 6, jj = idx & 63;
    float x = tile[jj * 65 + e];
    ushort h = bf16h(x);
    size_t o = ((size_t)head * DHEAD + e) * NFEAT + jb * 64 + jj;
    ctxThi[o] = h;
    ctxTlo[o] = bf16h(x - bf16f(h));
  }
}

// ---------------------------------------------------------------------------
// qout: TWO-PASS streamed form — kills the acc[16]+qp[16] register wall.
// Pass 1: hi-plane-only dd estimate -> row max mm (error ~0.25 scales qp
//   uniformly per row; cancels in num/den ratio except O(eps*delta)~2.5e-5).
// Pass 2: stream jt: dd tile (6 MFMA32, dual chains) -> exp -> qp pack ->
//   12 MFMA16 into oacc[4]; nothing else stays live.
// 256 blocks x 512 thr, (512,2); zero main-loop barriers; LDS 129 KB.
// ---------------------------------------------------------------------------
__global__ __launch_bounds__(512, 2) void qout_kernel(
    const float* __restrict__ qq, const ushort* __restrict__ P2hi,
    const ushort* __restrict__ P2lo, const float* __restrict__ ksum,
    const ushort* __restrict__ ctxThi, const ushort* __restrict__ ctxTlo,
    float* __restrict__ out) {
  __shared__ __align__(16) ushort PhiL[NFEAT * DHEAD];  // 32 KB
  __shared__ __align__(16) ushort PloL[NFEAT * DHEAD];  // 32 KB
  __shared__ __align__(16) ushort CTh[DHEAD * NFEAT];   // 32 KB (swizzled)
  __shared__ __align__(16) ushort CTl[DHEAD * NFEAT];   // 32 KB (swizzled)
  __shared__ float ksumL[NFEAT];                        // 1 KB
  const int t = threadIdx.x, lane = t & 63, w = t >> 6;
  const int cl = lane & 15, q = lane >> 4;
  const int head = blockIdx.x >> 3, slab = blockIdx.x & 7;
  for (int i = t; i < 2048; i += 512) {
    ((float4*)PhiL)[i] = ((const float4*)P2hi)[i];
    ((float4*)PloL)[i] = ((const float4*)P2lo)[i];
  }
  {  // stage ctxT with XOR swizzle (4-ushort groups stay contiguous)
    const size_t cb = (size_t)head * DHEAD * NFEAT;
    for (int g = t; g < 4096; g += 512) {
      int e = g >> 6, j4 = (g & 63) << 2;
      uint2 hv = *(const uint2*)(ctxThi + cb + e * NFEAT + j4);
      uint2 lv = *(const uint2*)(ctxTlo + cb + e * NFEAT + j4);
      int dst = e * NFEAT + (j4 ^ ((e & 15) << 2));
      *(uint2*)&CTh[dst] = hv;
      *(uint2*)&CTl[dst] = lv;
    }
  }
  if (t < NFEAT) ksumL[t] = ksum[head * NFEAT + t];
  __syncthreads();

  for (int s = 0; s < 4; ++s) {
    const int rb = slab * 512 + (w + s * 8) * 16;
    // B-frags: Q rows (col = n = cl), k = d
    const float* xb = qq + ((size_t)(head * NSEQ + rb + cl)) * DHEAD + q * 8;
    float4 pa0 = *(const float4*)(xb);
    float4 pa1 = *(const float4*)(xb + 4);
    float4 pa2 = *(const float4*)(xb + 32);
    float4 pa3 = *(const float4*)(xb + 36);
    float af[2][8] = {{pa0.x, pa0.y, pa0.z, pa0.w, pa1.x, pa1.y, pa1.z, pa1.w},
                      {pa2.x, pa2.y, pa2.z, pa2.w, pa3.x, pa3.y, pa3.z, pa3.w}};
    Frag8 bh[2], bl[2];
    float ssq = 0.f;
#pragma unroll
    for (int ks = 0; ks < 2; ++ks)
#pragma unroll
      for (int i = 0; i < 8; ++i) {
        float x = af[ks][i];
        ssq = fmaf(x, x, ssq);
        ushort h = bf16h(x);
        bh[ks].u[i] = h;
        bl[ks].u[i] = bf16h(x - bf16f(h));
      }
    float s2 = ssq;
    s2 += __shfl_xor(s2, 16);
    s2 += __shfl_xor(s2, 32);  // full ssq of row cl (lane-local diag)
    // ---- pass 1: hi-only row-max estimate (nothing stays live) ----
    float mr = -3.0e38f;
#pragma unroll
    for (int jt = 0; jt < 16; ++jt) {
      v4f a = (v4f){0.f, 0.f, 0.f, 0.f};
      a = MFMA32(*(const v8s*)&PhiL[((0 * 4 + q) * NFEAT + jt * 16 + cl) * 8],
                 bh[0].v, a);
      a = MFMA32(*(const v8s*)&PhiL[((1 * 4 + q) * NFEAT + jt * 16 + cl) * 8],
                 bh[1].v, a);
      mr = fmaxf(fmaxf(fmaxf(mr, a[0]), fmaxf(a[1], a[2])), a[3]);
    }
    mr = fmaxf(mr, __shfl_xor(mr, 16));
    mr = fmaxf(mr, __shfl_xor(mr, 32));
    const float mm = mr + DIAG_C * s2;
    // ---- pass 2: streamed dd -> qp -> PV ----
    v4f oacc[4];
#pragma unroll
    for (int et = 0; et < 4; ++et) oacc[et] = (v4f){0.f, 0.f, 0.f, 0.f};
    float ds = 0.f;
#pragma unroll
    for (int jt = 0; jt < 16; ++jt) {
      v4f aA = (v4f){0.f, 0.f, 0.f, 0.f};
      v4f aB = (v4f){0.f, 0.f, 0.f, 0.f};
      {
        const int p0 = ((0 * 4 + q) * NFEAT + jt * 16 + cl) * 8;
        const int p1 = ((1 * 4 + q) * NFEAT + jt * 16 + cl) * 8;
        v8s pAh0 = *(const v8s*)&PhiL[p0];
        v8s pAl0 = *(const v8s*)&PloL[p0];
        v8s pAh1 = *(const v8s*)&PhiL[p1];
        v8s pAl1 = *(const v8s*)&PloL[p1];
        aA = MFMA32(pAh0, bh[0].v, aA);
        aB = MFMA32(pAh1, bh[1].v, aB);
        aA = MFMA32(pAh0, bl[0].v, aA);
        aB = MFMA32(pAh1, bl[1].v, aB);
        aA = MFMA32(pAl0, bh[0].v, aA);
        aB = MFMA32(pAl1, bh[1].v, aB);
      }
      Frag4 qph, qpl;
#pragma unroll
      for (int r = 0; r < 4; ++r) {
        float a = aA[r] + aB[r];
        float qv = RATIO_C * (__expf(a - mm) + KEPS_C);
        ds = fmaf(qv, ksumL[jt * 16 + q * 4 + r], ds);
        ushort h = bf16h(qv);
        qph.u[r] = h;
        qpl.u[r] = bf16h(qv - bf16f(h));
      }
#pragma unroll
      for (int et = 0; et < 4; ++et) {
        const int ci = (et * 16 + cl) * NFEAT + ((jt * 16 + q * 4) ^ (cl << 2));
        v4s cth = *(const v4s*)&CTh[ci];
        v4s ctl = *(const v4s*)&CTl[ci];
        oacc[et] = MFMA16(cth, qph.v, oacc[et]);
        oacc[et] = MFMA16(cth, qpl.v, oacc[et]);
        oacc[et] = MFMA16(ctl, qph.v, oacc[et]);
      }
    }
    ds += __shfl_xor(ds, 16);
    ds += __shfl_xor(ds, 32);
    const float dinv = 1.0f / ds;
    // C: lane(cl,q) = outT[e=et*16+q*4+r][n=cl] -> float4 store per et
    float* ob = out + ((size_t)(head * NSEQ + rb + cl)) * DHEAD;
#pragma unroll
    for (int et = 0; et < 4; ++et) {
      float4 o;
      o.x = oacc[et][0] * dinv;
      o.y = oacc[et][1] * dinv;
      o.z = oacc[et][2] * dinv;
      o.w = oacc[et][3] * dinv;
      *(float4*)(ob + et * 16 + q * 4) = o;
    }
  }
}

extern "C" void kernel_launch(void* const* d_in, const int* in_sizes, int n_in,
                              void* d_out, int out_size, void* d_ws, size_t ws_size,
                              hipStream_t stream) {
  (void)in_sizes; (void)n_in; (void)out_size; (void)ws_size;
  const float* q = (const float*)d_in[0];
  const float* k = (const float*)d_in[1];
  const float* v = (const float*)d_in[2];
  const float* proj = (const float*)d_in[3];
  float* out = (float*)d_out;
  unsigned char* ws = (unsigned char*)d_ws;
  unsigned* kmax_u = (unsigned*)ws;                    // @0
  float* ksum = (float*)(ws + 256);                    // 32 KB
  float* ctx = (float*)(ws + 33024);                   // 2 MB
  ushort* P2hi = (ushort*)(ws + 2130176);              // 32 KB
  ushort* P2lo = (ushort*)(ws + 2162944);              // 32 KB
  ushort* ctxThi = (ushort*)(ws + 2195712);            // 1 MB
  ushort* ctxTlo = (ushort*)(ws + 3244288);            // 1 MB -> end 4292864
  (void)hipMemsetAsync(d_ws, 0, 2130176, stream);  // kmax_u + ksum + ctx
  hipLaunchKernelGGL(prep_kernel, dim3(64), dim3(256), 0, stream, proj, P2hi, P2lo);
  hipLaunchKernelGGL(kmax_kernel, dim3(512), dim3(512), 0, stream, k, P2hi,
                     kmax_u);
  hipLaunchKernelGGL(kctx_kernel, dim3(256), dim3(512), 0, stream, k, v, P2hi,
                     P2lo, kmax_u, ksum, ctx);
  hipLaunchKernelGGL(ctxprep_kernel, dim3(128), dim3(256), 0, stream, ctx,
                     ctxThi, ctxTlo);
  hipLaunchKernelGGL(qout_kernel, dim3(256), dim3(512), 0, stream, q, P2hi,
                     P2lo, ksum, ctxThi, ctxTlo, out);
}

// Round 7
// 405.431 us; speedup vs baseline: 1.9693x; 1.1863x over previous
//
#include <hip/hip_runtime.h>

#define NFEAT 256
#define DHEAD 64
#define NSEQ  4096

constexpr float NORM_C  = 0.35355339059327373f;  // 64^-0.25
constexpr float RATIO_C = 0.0625f;               // 256^-0.5
constexpr float DIAG_C  = 0.0625f;               // 0.5 * 64^-0.5
constexpr float KEPS_C  = 1e-4f;

using v8s = __attribute__((ext_vector_type(8))) short;
using v4s = __attribute__((ext_vector_type(4))) short;
using v4f = __attribute__((ext_vector_type(4))) float;
union Frag8 { v8s v; ushort u[8]; };
union Frag4 { v4s v; ushort u[4]; };

__device__ __forceinline__ ushort bf16h(float x) {
  unsigned u = __float_as_uint(x);
  return (ushort)((u + 0x7FFFu + ((u >> 16) & 1)) >> 16);
}
__device__ __forceinline__ float bf16f(ushort h) {
  return __uint_as_float(((unsigned)h) << 16);
}
__device__ __forceinline__ unsigned enc_f(float f) {
  unsigned u = __float_as_uint(f);
  return (u & 0x80000000u) ? ~u : (u | 0x80000000u);
}
__device__ __forceinline__ float dec_f(unsigned e) {
  return (e & 0x80000000u) ? __uint_as_float(e ^ 0x80000000u) : __uint_as_float(~e);
}

#define MFMA32(a, b, c) __builtin_amdgcn_mfma_f32_16x16x32_bf16((a), (b), (c), 0, 0, 0)
// gfx90a+/gfx950 K=16 bf16 MFMA; __has_builtin unreliable in host pass.
#if defined(__HIP_DEVICE_COMPILE__)
#define MFMA16(a, b, c) __builtin_amdgcn_mfma_f32_16x16x16bf16_1k((a), (b), (c), 0, 0, 0)
#else
#define MFMA16(a, b, c) (c)
#endif

// P (NORM folded) -> bf16 hi/lo planes, FRAGMENT-MAJOR:
//   P2[(d>>3)*256*8 + j*8 + (d&7)]
__global__ void prep_kernel(const float* __restrict__ proj,
                            ushort* __restrict__ P2hi, ushort* __restrict__ P2lo) {
  int i = blockIdx.x * 256 + threadIdx.x;
  if (i < NFEAT * DHEAD) {
    int j = i >> 6, d = i & 63;
    float x = NORM_C * proj[i];
    ushort h = bf16h(x);
    int off = ((d >> 3) * NFEAT + j) * 8 + (d & 7);
    P2hi[off] = h;
    P2lo[off] = bf16h(x - bf16f(h));
  }
}

// ---------------------------------------------------------------------------
// kmax (unchanged, passed 4x): global max of dd_k via MFMA, single bf16
// plane. 512 blocks x 512 thr, LDS 32 KB, 2 blocks/CU.
// ---------------------------------------------------------------------------
__global__ __launch_bounds__(512, 4) void kmax_kernel(
    const float* __restrict__ kk, const ushort* __restrict__ P2hi,
    unsigned* __restrict__ kmax_u) {
  __shared__ __align__(16) ushort PhiL[NFEAT * DHEAD];  // 32 KB
  __shared__ float wred[8];
  const int t = threadIdx.x, lane = t & 63, w = t >> 6;
  const int cl = lane & 15, q = lane >> 4;
  const int mw = w & 1, jq = w >> 1;
  const int head = blockIdx.x >> 4, slab = blockIdx.x & 15;
  for (int i = t; i < 2048; i += 512)
    ((float4*)PhiL)[i] = ((const float4*)P2hi)[i];
  const float* abase =
      kk + ((size_t)(head * NSEQ + slab * 256 + mw * 16 + cl)) * DHEAD + q * 8;
  float4 pa0 = *(const float4*)(abase);
  float4 pa1 = *(const float4*)(abase + 4);
  float4 pa2 = *(const float4*)(abase + 32);
  float4 pa3 = *(const float4*)(abase + 36);
  __syncthreads();
  float mx = -3.0e38f;
  for (int c = 0; c < 8; ++c) {
    float af[2][8] = {{pa0.x, pa0.y, pa0.z, pa0.w, pa1.x, pa1.y, pa1.z, pa1.w},
                      {pa2.x, pa2.y, pa2.z, pa2.w, pa3.x, pa3.y, pa3.z, pa3.w}};
    Frag8 ah[2];
#pragma unroll
    for (int ks = 0; ks < 2; ++ks)
#pragma unroll
      for (int i = 0; i < 8; ++i) ah[ks].u[i] = bf16h(af[ks][i]);
    if (c < 7) {
      const float* nx = abase + (size_t)(c + 1) * 32 * DHEAD;
      pa0 = *(const float4*)(nx);
      pa1 = *(const float4*)(nx + 4);
      pa2 = *(const float4*)(nx + 32);
      pa3 = *(const float4*)(nx + 36);
    }
    v4f acc[4];
#pragma unroll
    for (int jt = 0; jt < 4; ++jt) acc[jt] = (v4f){0.f, 0.f, 0.f, 0.f};
#pragma unroll
    for (int ks = 0; ks < 2; ++ks)
#pragma unroll
      for (int jt = 0; jt < 4; ++jt) {
        v8s bh = *(const v8s*)&PhiL[((ks * 4 + q) * NFEAT + jq * 64 + jt * 16 + cl) * 8];
        acc[jt] = MFMA32(ah[ks].v, bh, acc[jt]);
      }
#pragma unroll
    for (int jt = 0; jt < 4; ++jt)
#pragma unroll
      for (int r = 0; r < 4; ++r) mx = fmaxf(mx, acc[jt][r]);
  }
  for (int s = 1; s < 64; s <<= 1) mx = fmaxf(mx, __shfl_xor(mx, s));
  if (lane == 0) wred[w] = mx;
  __syncthreads();
  if (t == 0) {
    float r = wred[0];
#pragma unroll
    for (int i = 1; i < 8; ++i) r = fmaxf(r, wred[i]);
    atomicMax(kmax_u, enc_f(r));
  }
}

// ---------------------------------------------------------------------------
// kctx: barrier-free transpose-trick, 512 thr, (512,2), K/V reg prefetch.
// jt loop capped at unroll 2 to bound the scheduler's LDS-load hoisting
// window (full unroll -> hoist-then-spill, the round-5/6 failure mode).
// ---------------------------------------------------------------------------
__global__ __launch_bounds__(512, 2) void kctx_kernel(
    const float* __restrict__ kk, const float* __restrict__ vv,
    const ushort* __restrict__ P2hi, const ushort* __restrict__ P2lo,
    const unsigned* __restrict__ kmax_u, float* __restrict__ ksum,
    float* __restrict__ ctx) {
  __shared__ __align__(16) ushort PhiL[NFEAT * DHEAD];  // 32 KB
  __shared__ __align__(16) ushort PloL[NFEAT * DHEAD];  // 32 KB
  const int t = threadIdx.x, lane = t & 63, w = t >> 6;
  const int cl = lane & 15, q = lane >> 4;
  const int jq = w & 3, rg = w >> 2;
  const int head = blockIdx.x >> 3, slab = blockIdx.x & 7;
  const float m = dec_f(*kmax_u);
  for (int i = t; i < 2048; i += 512) {
    ((float4*)PhiL)[i] = ((const float4*)P2hi)[i];
    ((float4*)PloL)[i] = ((const float4*)P2lo)[i];
  }
  __syncthreads();
  float ksacc[4] = {0.f, 0.f, 0.f, 0.f};
  v4f ctxacc[4][4];  // [jt][et]
#pragma unroll
  for (int jt = 0; jt < 4; ++jt)
#pragma unroll
    for (int et = 0; et < 4; ++et) ctxacc[jt][et] = (v4f){0.f, 0.f, 0.f, 0.f};

  const float* abase =
      kk + ((size_t)(head * NSEQ + slab * 512 + rg * 16 + cl)) * DHEAD + q * 8;
  const float* vbase =
      vv + ((size_t)(head * NSEQ + slab * 512 + rg * 16 + q * 4)) * DHEAD + cl;
  float4 pa0 = *(const float4*)(abase);
  float4 pa1 = *(const float4*)(abase + 4);
  float4 pa2 = *(const float4*)(abase + 32);
  float4 pa3 = *(const float4*)(abase + 36);
  float vr[16];
#pragma unroll
  for (int u = 0; u < 16; ++u) vr[u] = vbase[(u & 3) * DHEAD + (u >> 2) * 16];

  for (int cc = 0; cc < 16; ++cc) {
    float af[2][8] = {{pa0.x, pa0.y, pa0.z, pa0.w, pa1.x, pa1.y, pa1.z, pa1.w},
                      {pa2.x, pa2.y, pa2.z, pa2.w, pa3.x, pa3.y, pa3.z, pa3.w}};
    Frag8 ah[2], al[2];
    float ssq = 0.f;
#pragma unroll
    for (int ks = 0; ks < 2; ++ks)
#pragma unroll
      for (int i = 0; i < 8; ++i) {
        float x = af[ks][i];
        ssq = fmaf(x, x, ssq);
        ushort h = bf16h(x);
        ah[ks].u[i] = h;
        al[ks].u[i] = bf16h(x - bf16f(h));
      }
    Frag4 bvh[4], bvl[4];
#pragma unroll
    for (int et = 0; et < 4; ++et)
#pragma unroll
      for (int i = 0; i < 4; ++i) {
        float x = vr[et * 4 + i];
        ushort h = bf16h(x);
        bvh[et].u[i] = h;
        bvl[et].u[i] = bf16h(x - bf16f(h));
      }
    if (cc < 15) {  // prefetch next step's K and V into registers
      const float* nx = abase + (size_t)(cc + 1) * 32 * DHEAD;
      pa0 = *(const float4*)(nx);
      pa1 = *(const float4*)(nx + 4);
      pa2 = *(const float4*)(nx + 32);
      pa3 = *(const float4*)(nx + 36);
      const float* nv = vbase + (size_t)(cc + 1) * 32 * DHEAD;
#pragma unroll
      for (int u = 0; u < 16; ++u) vr[u] = nv[(u & 3) * DHEAD + (u >> 2) * 16];
    }
    float s2 = ssq;
    s2 += __shfl_xor(s2, 16);
    s2 += __shfl_xor(s2, 32);  // full ssq of row cl at every lane
    float dg[4];
#pragma unroll
    for (int r = 0; r < 4; ++r) dg[r] = DIAG_C * __shfl(s2, q * 4 + r);
    // stream jt: dd -> kp (one tile live) -> MFMA16 into ctxacc
#pragma unroll 2
    for (int jt = 0; jt < 4; ++jt) {
      v4f acc = (v4f){0.f, 0.f, 0.f, 0.f};
#pragma unroll
      for (int ks = 0; ks < 2; ++ks) {
        const int pidx = ((ks * 4 + q) * NFEAT + jq * 64 + jt * 16 + cl) * 8;
        v8s bh = *(const v8s*)&PhiL[pidx];
        v8s bl = *(const v8s*)&PloL[pidx];
        acc = MFMA32(ah[ks].v, bh, acc);
        acc = MFMA32(ah[ks].v, bl, acc);
        acc = MFMA32(al[ks].v, bh, acc);
      }
      Frag4 kph, kpl;
#pragma unroll
      for (int r = 0; r < 4; ++r) {
        float e_ = RATIO_C * (__expf(acc[r] - dg[r] - m) + KEPS_C);
        ksacc[jt] += e_;
        ushort h = bf16h(e_);
        kph.u[r] = h;
        kpl.u[r] = bf16h(e_ - bf16f(h));
      }
#pragma unroll
      for (int et = 0; et < 4; ++et) {
        ctxacc[jt][et] = MFMA16(kph.v, bvh[et].v, ctxacc[jt][et]);
        ctxacc[jt][et] = MFMA16(kph.v, bvl[et].v, ctxacc[jt][et]);
        ctxacc[jt][et] = MFMA16(kpl.v, bvh[et].v, ctxacc[jt][et]);
      }
    }
  }
#pragma unroll
  for (int jt = 0; jt < 4; ++jt) {
    float s = ksacc[jt];
    s += __shfl_xor(s, 16);
    s += __shfl_xor(s, 32);
    if (q == 0) atomicAdd(&ksum[head * NFEAT + jq * 64 + jt * 16 + cl], s);
  }
#pragma unroll
  for (int jt = 0; jt < 4; ++jt)
#pragma unroll
    for (int et = 0; et < 4; ++et)
#pragma unroll
      for (int r = 0; r < 4; ++r) {
        int j = jq * 64 + jt * 16 + q * 4 + r;
        int e = et * 16 + cl;
        atomicAdd(&ctx[((size_t)head * NFEAT + j) * DHEAD + e],
                  ctxacc[jt][et][r]);
      }
}

// ---------------------------------------------------------------------------
// ctxprep: ctx fp32 [h][j][e] -> ctxT bf16 hi/lo planes [h][e][j]
// ---------------------------------------------------------------------------
__global__ void ctxprep_kernel(const float* __restrict__ ctx,
                               ushort* __restrict__ ctxThi,
                               ushort* __restrict__ ctxTlo) {
  __shared__ float tile[64 * 65];
  const int head = blockIdx.x >> 2, jb = blockIdx.x & 3, t = threadIdx.x;
#pragma unroll
  for (int i = 0; i < 16; ++i) {
    int idx = t + i * 256;
    int jj = idx >> 6, e = idx & 63;
    tile[jj * 65 + e] = ctx[((size_t)head * NFEAT + jb * 64 + jj) * DHEAD + e];
  }
  __syncthreads();
#pragma unroll
  for (int i = 0; i < 16; ++i) {
    int idx = t + i * 256;
    int e = idx >> 6, jj = idx & 63;
    float x = tile[jj * 65 + e];
    ushort h = bf16h(x);
    size_t o = ((size_t)head * DHEAD + e) * NFEAT + jb * 64 + jj;
    ctxThi[o] = h;
    ctxTlo[o] = bf16h(x - bf16f(h));
  }
}

// ---------------------------------------------------------------------------
// qout: two-pass streamed transpose-trick (math hw-verified rounds 4-6).
// Unroll caps bound the scheduler's hoist window: pass 1 unroll 2 (<=8
// P-frag regs in flight, vs 64 when fully unrolled), pass 2 unroll 1 (one
// jt tile live: ~40 regs + oacc). This is the anti-spill fix.
// 256 blocks x 512 thr, (512,2); zero main-loop barriers; LDS 129 KB.
// ---------------------------------------------------------------------------
__global__ __launch_bounds__(512, 2) void qout_kernel(
    const float* __restrict__ qq, const ushort* __restrict__ P2hi,
    const ushort* __restrict__ P2lo, const float* __restrict__ ksum,
    const ushort* __restrict__ ctxThi, const ushort* __restrict__ ctxTlo,
    float* __restrict__ out) {
  __shared__ __align__(16) ushort PhiL[NFEAT * DHEAD];  // 32 KB
  __shared__ __align__(16) ushort PloL[NFEAT * DHEAD];  // 32 KB
  __shared__ __align__(16) ushort CTh[DHEAD * NFEAT];   // 32 KB (swizzled)
  __shared__ __align__(16) ushort CTl[DHEAD * NFEAT];   // 32 KB (swizzled)
  __shared__ float ksumL[NFEAT];                        // 1 KB
  const int t = threadIdx.x, lane = t & 63, w = t >> 6;
  const int cl = lane & 15, q = lane >> 4;
  const int head = blockIdx.x >> 3, slab = blockIdx.x & 7;
  for (int i = t; i < 2048; i += 512) {
    ((float4*)PhiL)[i] = ((const float4*)P2hi)[i];
    ((float4*)PloL)[i] = ((const float4*)P2lo)[i];
  }
  {  // stage ctxT with XOR swizzle (4-ushort groups stay contiguous)
    const size_t cb = (size_t)head * DHEAD * NFEAT;
    for (int g = t; g < 4096; g += 512) {
      int e = g >> 6, j4 = (g & 63) << 2;
      uint2 hv = *(const uint2*)(ctxThi + cb + e * NFEAT + j4);
      uint2 lv = *(const uint2*)(ctxTlo + cb + e * NFEAT + j4);
      int dst = e * NFEAT + (j4 ^ ((e & 15) << 2));
      *(uint2*)&CTh[dst] = hv;
      *(uint2*)&CTl[dst] = lv;
    }
  }
  if (t < NFEAT) ksumL[t] = ksum[head * NFEAT + t];
  __syncthreads();

  for (int s = 0; s < 4; ++s) {
    const int rb = slab * 512 + (w + s * 8) * 16;
    // B-frags: Q rows (col = n = cl), k = d
    const float* xb = qq + ((size_t)(head * NSEQ + rb + cl)) * DHEAD + q * 8;
    float4 pa0 = *(const float4*)(xb);
    float4 pa1 = *(const float4*)(xb + 4);
    float4 pa2 = *(const float4*)(xb + 32);
    float4 pa3 = *(const float4*)(xb + 36);
    float af[2][8] = {{pa0.x, pa0.y, pa0.z, pa0.w, pa1.x, pa1.y, pa1.z, pa1.w},
                      {pa2.x, pa2.y, pa2.z, pa2.w, pa3.x, pa3.y, pa3.z, pa3.w}};
    Frag8 bh[2], bl[2];
    float ssq = 0.f;
#pragma unroll
    for (int ks = 0; ks < 2; ++ks)
#pragma unroll
      for (int i = 0; i < 8; ++i) {
        float x = af[ks][i];
        ssq = fmaf(x, x, ssq);
        ushort h = bf16h(x);
        bh[ks].u[i] = h;
        bl[ks].u[i] = bf16h(x - bf16f(h));
      }
    float s2 = ssq;
    s2 += __shfl_xor(s2, 16);
    s2 += __shfl_xor(s2, 32);  // full ssq of row cl (lane-local diag)
    // ---- pass 1: hi-only row-max estimate (unroll-capped) ----
    float mr = -3.0e38f;
#pragma unroll 2
    for (int jt = 0; jt < 16; ++jt) {
      v4f a = (v4f){0.f, 0.f, 0.f, 0.f};
      a = MFMA32(*(const v8s*)&PhiL[((0 * 4 + q) * NFEAT + jt * 16 + cl) * 8],
                 bh[0].v, a);
      a = MFMA32(*(const v8s*)&PhiL[((1 * 4 + q) * NFEAT + jt * 16 + cl) * 8],
                 bh[1].v, a);
      mr = fmaxf(fmaxf(fmaxf(mr, a[0]), fmaxf(a[1], a[2])), a[3]);
    }
    mr = fmaxf(mr, __shfl_xor(mr, 16));
    mr = fmaxf(mr, __shfl_xor(mr, 32));
    const float mm = mr + DIAG_C * s2;
    // ---- pass 2: streamed dd -> qp -> PV (unroll 1: one jt tile live) ----
    v4f oacc[4];
#pragma unroll
    for (int et = 0; et < 4; ++et) oacc[et] = (v4f){0.f, 0.f, 0.f, 0.f};
    float ds = 0.f;
#pragma unroll 1
    for (int jt = 0; jt < 16; ++jt) {
      v4f aA = (v4f){0.f, 0.f, 0.f, 0.f};
      v4f aB = (v4f){0.f, 0.f, 0.f, 0.f};
      {
        const int p0 = ((0 * 4 + q) * NFEAT + jt * 16 + cl) * 8;
        const int p1 = ((1 * 4 + q) * NFEAT + jt * 16 + cl) * 8;
        v8s pAh0 = *(const v8s*)&PhiL[p0];
        v8s pAl0 = *(const v8s*)&PloL[p0];
        v8s pAh1 = *(const v8s*)&PhiL[p1];
        v8s pAl1 = *(const v8s*)&PloL[p1];
        aA = MFMA32(pAh0, bh[0].v, aA);
        aB = MFMA32(pAh1, bh[1].v, aB);
        aA = MFMA32(pAh0, bl[0].v, aA);
        aB = MFMA32(pAh1, bl[1].v, aB);
        aA = MFMA32(pAl0, bh[0].v, aA);
        aB = MFMA32(pAl1, bh[1].v, aB);
      }
      Frag4 qph, qpl;
#pragma unroll
      for (int r = 0; r < 4; ++r) {
        float a = aA[r] + aB[r];
        float qv = RATIO_C * (__expf(a - mm) + KEPS_C);
        ds = fmaf(qv, ksumL[jt * 16 + q * 4 + r], ds);
        ushort h = bf16h(qv);
        qph.u[r] = h;
        qpl.u[r] = bf16h(qv - bf16f(h));
      }
#pragma unroll
      for (int et = 0; et < 4; ++et) {
        const int ci = (et * 16 + cl) * NFEAT + ((jt * 16 + q * 4) ^ (cl << 2));
        v4s cth = *(const v4s*)&CTh[ci];
        v4s ctl = *(const v4s*)&CTl[ci];
        oacc[et] = MFMA16(cth, qph.v, oacc[et]);
        oacc[et] = MFMA16(cth, qpl.v, oacc[et]);
        oacc[et] = MFMA16(ctl, qph.v, oacc[et]);
      }
    }
    ds += __shfl_xor(ds, 16);
    ds += __shfl_xor(ds, 32);
    const float dinv = 1.0f / ds;
    // C: lane(cl,q) = outT[e=et*16+q*4+r][n=cl] -> float4 store per et
    float* ob = out + ((size_t)(head * NSEQ + rb + cl)) * DHEAD;
#pragma unroll
    for (int et = 0; et < 4; ++et) {
      float4 o;
      o.x = oacc[et][0] * dinv;
      o.y = oacc[et][1] * dinv;
      o.z = oacc[et][2] * dinv;
      o.w = oacc[et][3] * dinv;
      *(float4*)(ob + et * 16 + q * 4) = o;
    }
  }
}

extern "C" void kernel_launch(void* const* d_in, const int* in_sizes, int n_in,
                              void* d_out, int out_size, void* d_ws, size_t ws_size,
                              hipStream_t stream) {
  (void)in_sizes; (void)n_in; (void)out_size; (void)ws_size;
  const float* q = (const float*)d_in[0];
  const float* k = (const float*)d_in[1];
  const float* v = (const float*)d_in[2];
  const float* proj = (const float*)d_in[3];
  float* out = (float*)d_out;
  unsigned char* ws = (unsigned char*)d_ws;
  unsigned* kmax_u = (unsigned*)ws;                    // @0
  float* ksum = (float*)(ws + 256);                    // 32 KB
  float* ctx = (float*)(ws + 33024);                   // 2 MB
  ushort* P2hi = (ushort*)(ws + 2130176);              // 32 KB
  ushort* P2lo = (ushort*)(ws + 2162944);              // 32 KB
  ushort* ctxThi = (ushort*)(ws + 2195712);            // 1 MB
  ushort* ctxTlo = (ushort*)(ws + 3244288);            // 1 MB -> end 4292864
  (void)hipMemsetAsync(d_ws, 0, 2130176, stream);  // kmax_u + ksum + ctx
  hipLaunchKernelGGL(prep_kernel, dim3(64), dim3(256), 0, stream, proj, P2hi, P2lo);
  hipLaunchKernelGGL(kmax_kernel, dim3(512), dim3(512), 0, stream, k, P2hi,
                     kmax_u);
  hipLaunchKernelGGL(kctx_kernel, dim3(256), dim3(512), 0, stream, k, v, P2hi,
                     P2lo, kmax_u, ksum, ctx);
  hipLaunchKernelGGL(ctxprep_kernel, dim3(128), dim3(256), 0, stream, ctx,
                     ctxThi, ctxTlo);
  hipLaunchKernelGGL(qout_kernel, dim3(256), dim3(512), 0, stream, q, P2hi,
                     P2lo, ksum, ctxThi, ctxTlo, out);
}

// Round 8
// 397.081 us; speedup vs baseline: 2.0107x; 1.0210x over previous
//
#include <hip/hip_runtime.h>

#define NFEAT 256
#define DHEAD 64
#define NSEQ  4096

constexpr float NORM_C  = 0.35355339059327373f;  // 64^-0.25
constexpr float RATIO_C = 0.0625f;               // 256^-0.5
constexpr float DIAG_C  = 0.0625f;               // 0.5 * 64^-0.5
constexpr float KEPS_C  = 1e-4f;

using v8s = __attribute__((ext_vector_type(8))) short;
using v4s = __attribute__((ext_vector_type(4))) short;
using v4f = __attribute__((ext_vector_type(4))) float;
union Frag8 { v8s v; ushort u[8]; };
union Frag4 { v4s v; ushort u[4]; };

__device__ __forceinline__ ushort bf16h(float x) {
  unsigned u = __float_as_uint(x);
  return (ushort)((u + 0x7FFFu + ((u >> 16) & 1)) >> 16);
}
__device__ __forceinline__ float bf16f(ushort h) {
  return __uint_as_float(((unsigned)h) << 16);
}
__device__ __forceinline__ unsigned enc_f(float f) {
  unsigned u = __float_as_uint(f);
  return (u & 0x80000000u) ? ~u : (u | 0x80000000u);
}
__device__ __forceinline__ float dec_f(unsigned e) {
  return (e & 0x80000000u) ? __uint_as_float(e ^ 0x80000000u) : __uint_as_float(~e);
}

#define MFMA32(a, b, c) __builtin_amdgcn_mfma_f32_16x16x32_bf16((a), (b), (c), 0, 0, 0)
// gfx90a+/gfx950 K=16 bf16 MFMA; __has_builtin unreliable in host pass.
#if defined(__HIP_DEVICE_COMPILE__)
#define MFMA16(a, b, c) __builtin_amdgcn_mfma_f32_16x16x16bf16_1k((a), (b), (c), 0, 0, 0)
#else
#define MFMA16(a, b, c) (c)
#endif

// P (NORM folded) -> bf16 hi/lo planes, FRAGMENT-MAJOR:
//   P2[(d>>3)*256*8 + j*8 + (d&7)]
__global__ void prep_kernel(const float* __restrict__ proj,
                            ushort* __restrict__ P2hi, ushort* __restrict__ P2lo) {
  int i = blockIdx.x * 256 + threadIdx.x;
  if (i < NFEAT * DHEAD) {
    int j = i >> 6, d = i & 63;
    float x = NORM_C * proj[i];
    ushort h = bf16h(x);
    int off = ((d >> 3) * NFEAT + j) * 8 + (d & 7);
    P2hi[off] = h;
    P2lo[off] = bf16h(x - bf16f(h));
  }
}

// ---------------------------------------------------------------------------
// kmax (unchanged, passed 5x): global max of dd_k via MFMA, single bf16
// plane. 512 blocks x 512 thr, LDS 32 KB, 2 blocks/CU.
// ---------------------------------------------------------------------------
__global__ __launch_bounds__(512, 4) void kmax_kernel(
    const float* __restrict__ kk, const ushort* __restrict__ P2hi,
    unsigned* __restrict__ kmax_u) {
  __shared__ __align__(16) ushort PhiL[NFEAT * DHEAD];  // 32 KB
  __shared__ float wred[8];
  const int t = threadIdx.x, lane = t & 63, w = t >> 6;
  const int cl = lane & 15, q = lane >> 4;
  const int mw = w & 1, jq = w >> 1;
  const int head = blockIdx.x >> 4, slab = blockIdx.x & 15;
  for (int i = t; i < 2048; i += 512)
    ((float4*)PhiL)[i] = ((const float4*)P2hi)[i];
  const float* abase =
      kk + ((size_t)(head * NSEQ + slab * 256 + mw * 16 + cl)) * DHEAD + q * 8;
  float4 pa0 = *(const float4*)(abase);
  float4 pa1 = *(const float4*)(abase + 4);
  float4 pa2 = *(const float4*)(abase + 32);
  float4 pa3 = *(const float4*)(abase + 36);
  __syncthreads();
  float mx = -3.0e38f;
  for (int c = 0; c < 8; ++c) {
    float af[2][8] = {{pa0.x, pa0.y, pa0.z, pa0.w, pa1.x, pa1.y, pa1.z, pa1.w},
                      {pa2.x, pa2.y, pa2.z, pa2.w, pa3.x, pa3.y, pa3.z, pa3.w}};
    Frag8 ah[2];
#pragma unroll
    for (int ks = 0; ks < 2; ++ks)
#pragma unroll
      for (int i = 0; i < 8; ++i) ah[ks].u[i] = bf16h(af[ks][i]);
    if (c < 7) {
      const float* nx = abase + (size_t)(c + 1) * 32 * DHEAD;
      pa0 = *(const float4*)(nx);
      pa1 = *(const float4*)(nx + 4);
      pa2 = *(const float4*)(nx + 32);
      pa3 = *(const float4*)(nx + 36);
    }
    v4f acc[4];
#pragma unroll
    for (int jt = 0; jt < 4; ++jt) acc[jt] = (v4f){0.f, 0.f, 0.f, 0.f};
#pragma unroll
    for (int ks = 0; ks < 2; ++ks)
#pragma unroll
      for (int jt = 0; jt < 4; ++jt) {
        v8s bh = *(const v8s*)&PhiL[((ks * 4 + q) * NFEAT + jq * 64 + jt * 16 + cl) * 8];
        acc[jt] = MFMA32(ah[ks].v, bh, acc[jt]);
      }
#pragma unroll
    for (int jt = 0; jt < 4; ++jt)
#pragma unroll
      for (int r = 0; r < 4; ++r) mx = fmaxf(mx, acc[jt][r]);
  }
  for (int s = 1; s < 64; s <<= 1) mx = fmaxf(mx, __shfl_xor(mx, s));
  if (lane == 0) wred[w] = mx;
  __syncthreads();
  if (t == 0) {
    float r = wred[0];
#pragma unroll
    for (int i = 1; i < 8; ++i) r = fmaxf(r, wred[i]);
    atomicMax(kmax_u, enc_f(r));
  }
}

// ---------------------------------------------------------------------------
// kctx main body (shared by both epilogue variants). Round-7 hw-verified.
// PARTIAL=1: no ctx atomics — rg-pair reduction through the P LDS buffer,
//   then plain coalesced stores of the (head,slab) partial into ctxpart.
// PARTIAL=0: round-7 atomic epilogue (fallback when workspace too small).
// ---------------------------------------------------------------------------
template <int PARTIAL>
__global__ __launch_bounds__(512, 2) void kctx_kernel_t(
    const float* __restrict__ kk, const float* __restrict__ vv,
    const ushort* __restrict__ P2hi, const ushort* __restrict__ P2lo,
    const unsigned* __restrict__ kmax_u, float* __restrict__ ksum,
    float* __restrict__ ctxout) {
  __shared__ __align__(16) ushort Pbuf[2][NFEAT * DHEAD];  // 64 KB
  ushort* PhiL = Pbuf[0];
  ushort* PloL = Pbuf[1];
  const int t = threadIdx.x, lane = t & 63, w = t >> 6;
  const int cl = lane & 15, q = lane >> 4;
  const int jq = w & 3, rg = w >> 2;
  const int head = blockIdx.x >> 3, slab = blockIdx.x & 7;
  const float m = dec_f(*kmax_u);
  for (int i = t; i < 2048; i += 512) {
    ((float4*)PhiL)[i] = ((const float4*)P2hi)[i];
    ((float4*)PloL)[i] = ((const float4*)P2lo)[i];
  }
  __syncthreads();
  float ksacc[4] = {0.f, 0.f, 0.f, 0.f};
  v4f ctxacc[4][4];  // [jt][et]
#pragma unroll
  for (int jt = 0; jt < 4; ++jt)
#pragma unroll
    for (int et = 0; et < 4; ++et) ctxacc[jt][et] = (v4f){0.f, 0.f, 0.f, 0.f};

  const float* abase =
      kk + ((size_t)(head * NSEQ + slab * 512 + rg * 16 + cl)) * DHEAD + q * 8;
  const float* vbase =
      vv + ((size_t)(head * NSEQ + slab * 512 + rg * 16 + q * 4)) * DHEAD + cl;
  float4 pa0 = *(const float4*)(abase);
  float4 pa1 = *(const float4*)(abase + 4);
  float4 pa2 = *(const float4*)(abase + 32);
  float4 pa3 = *(const float4*)(abase + 36);
  float vr[16];
#pragma unroll
  for (int u = 0; u < 16; ++u) vr[u] = vbase[(u & 3) * DHEAD + (u >> 2) * 16];

  for (int cc = 0; cc < 16; ++cc) {
    float af[2][8] = {{pa0.x, pa0.y, pa0.z, pa0.w, pa1.x, pa1.y, pa1.z, pa1.w},
                      {pa2.x, pa2.y, pa2.z, pa2.w, pa3.x, pa3.y, pa3.z, pa3.w}};
    Frag8 ah[2], al[2];
    float ssq = 0.f;
#pragma unroll
    for (int ks = 0; ks < 2; ++ks)
#pragma unroll
      for (int i = 0; i < 8; ++i) {
        float x = af[ks][i];
        ssq = fmaf(x, x, ssq);
        ushort h = bf16h(x);
        ah[ks].u[i] = h;
        al[ks].u[i] = bf16h(x - bf16f(h));
      }
    Frag4 bvh[4], bvl[4];
#pragma unroll
    for (int et = 0; et < 4; ++et)
#pragma unroll
      for (int i = 0; i < 4; ++i) {
        float x = vr[et * 4 + i];
        ushort h = bf16h(x);
        bvh[et].u[i] = h;
        bvl[et].u[i] = bf16h(x - bf16f(h));
      }
    if (cc < 15) {  // prefetch next step's K and V into registers
      const float* nx = abase + (size_t)(cc + 1) * 32 * DHEAD;
      pa0 = *(const float4*)(nx);
      pa1 = *(const float4*)(nx + 4);
      pa2 = *(const float4*)(nx + 32);
      pa3 = *(const float4*)(nx + 36);
      const float* nv = vbase + (size_t)(cc + 1) * 32 * DHEAD;
#pragma unroll
      for (int u = 0; u < 16; ++u) vr[u] = nv[(u & 3) * DHEAD + (u >> 2) * 16];
    }
    float s2 = ssq;
    s2 += __shfl_xor(s2, 16);
    s2 += __shfl_xor(s2, 32);  // full ssq of row cl at every lane
    float dg[4];
#pragma unroll
    for (int r = 0; r < 4; ++r) dg[r] = DIAG_C * __shfl(s2, q * 4 + r);
    // stream jt: dd -> kp (one tile live) -> MFMA16 into ctxacc
#pragma unroll 2
    for (int jt = 0; jt < 4; ++jt) {
      v4f acc = (v4f){0.f, 0.f, 0.f, 0.f};
#pragma unroll
      for (int ks = 0; ks < 2; ++ks) {
        const int pidx = ((ks * 4 + q) * NFEAT + jq * 64 + jt * 16 + cl) * 8;
        v8s bh = *(const v8s*)&PhiL[pidx];
        v8s bl = *(const v8s*)&PloL[pidx];
        acc = MFMA32(ah[ks].v, bh, acc);
        acc = MFMA32(ah[ks].v, bl, acc);
        acc = MFMA32(al[ks].v, bh, acc);
      }
      Frag4 kph, kpl;
#pragma unroll
      for (int r = 0; r < 4; ++r) {
        float e_ = RATIO_C * (__expf(acc[r] - dg[r] - m) + KEPS_C);
        ksacc[jt] += e_;
        ushort h = bf16h(e_);
        kph.u[r] = h;
        kpl.u[r] = bf16h(e_ - bf16f(h));
      }
#pragma unroll
      for (int et = 0; et < 4; ++et) {
        ctxacc[jt][et] = MFMA16(kph.v, bvh[et].v, ctxacc[jt][et]);
        ctxacc[jt][et] = MFMA16(kph.v, bvl[et].v, ctxacc[jt][et]);
        ctxacc[jt][et] = MFMA16(kpl.v, bvh[et].v, ctxacc[jt][et]);
      }
    }
  }
#pragma unroll
  for (int jt = 0; jt < 4; ++jt) {
    float s = ksacc[jt];
    s += __shfl_xor(s, 16);
    s += __shfl_xor(s, 32);
    if (q == 0) atomicAdd(&ksum[head * NFEAT + jq * 64 + jt * 16 + cl], s);
  }
  if (PARTIAL) {
    // rg-pair reduction through the (now-dead) P LDS buffer, then plain
    // coalesced stores of this (head,slab) partial. Zero ctx atomics.
    __syncthreads();  // everyone done reading Pbuf
    float* red = (float*)&Pbuf[0][0];  // 16384 floats = 64 KB
    if (rg == 1) {
#pragma unroll
      for (int jt = 0; jt < 4; ++jt)
#pragma unroll
        for (int et = 0; et < 4; ++et)
#pragma unroll
          for (int r = 0; r < 4; ++r)
            red[jq * 4096 + (jt * 16 + q * 4 + r) * 64 + et * 16 + cl] =
                ctxacc[jt][et][r];
    }
    __syncthreads();
    if (rg == 0) {
      float* base = ctxout + (size_t)(head * 8 + slab) * (NFEAT * DHEAD);
#pragma unroll
      for (int jt = 0; jt < 4; ++jt)
#pragma unroll
        for (int et = 0; et < 4; ++et)
#pragma unroll
          for (int r = 0; r < 4; ++r) {
            const int jl = jt * 16 + q * 4 + r;
            const int e = et * 16 + cl;
            base[(jq * 64 + jl) * DHEAD + e] =
                ctxacc[jt][et][r] + red[jq * 4096 + jl * 64 + e];
          }
    }
  } else {
#pragma unroll
    for (int jt = 0; jt < 4; ++jt)
#pragma unroll
      for (int et = 0; et < 4; ++et)
#pragma unroll
        for (int r = 0; r < 4; ++r) {
          int j = jq * 64 + jt * 16 + q * 4 + r;
          int e = et * 16 + cl;
          atomicAdd(&ctxout[((size_t)head * NFEAT + j) * DHEAD + e],
                    ctxacc[jt][et][r]);
        }
  }
}

// ---------------------------------------------------------------------------
// ctxprep (fallback): ctx fp32 [h][j][e] -> ctxT bf16 hi/lo planes [h][e][j]
// ---------------------------------------------------------------------------
__global__ void ctxprep_kernel(const float* __restrict__ ctx,
                               ushort* __restrict__ ctxThi,
                               ushort* __restrict__ ctxTlo) {
  __shared__ float tile[64 * 65];
  const int head = blockIdx.x >> 2, jb = blockIdx.x & 3, t = threadIdx.x;
#pragma unroll
  for (int i = 0; i < 16; ++i) {
    int idx = t + i * 256;
    int jj = idx >> 6, e = idx & 63;
    tile[jj * 65 + e] = ctx[((size_t)head * NFEAT + jb * 64 + jj) * DHEAD + e];
  }
  __syncthreads();
#pragma unroll
  for (int i = 0; i < 16; ++i) {
    int idx = t + i * 256;
    int e = idx >> 6, jj = idx & 63;
    float x = tile[jj * 65 + e];
    ushort h = bf16h(x);
    size_t o = ((size_t)head * DHEAD + e) * NFEAT + jb * 64 + jj;
    ctxThi[o] = h;
    ctxTlo[o] = bf16h(x - bf16f(h));
  }
}

// ---------------------------------------------------------------------------
// ctxprep_red: sum 8 slab partials -> ctxT bf16 hi/lo planes [h][e][j]
// ---------------------------------------------------------------------------
__global__ void ctxprep_red_kernel(const float* __restrict__ ctxpart,
                                   ushort* __restrict__ ctxThi,
                                   ushort* __restrict__ ctxTlo) {
  __shared__ float tile[64 * 65];
  const int head = blockIdx.x >> 2, jb = blockIdx.x & 3, t = threadIdx.x;
  const float* base = ctxpart + (size_t)head * 8 * (NFEAT * DHEAD);
#pragma unroll
  for (int i = 0; i < 16; ++i) {
    int idx = t + i * 256;
    int jj = idx >> 6, e = idx & 63;
    const int off = (jb * 64 + jj) * DHEAD + e;
    float s = 0.f;
#pragma unroll
    for (int sl = 0; sl < 8; ++sl) s += base[(size_t)sl * (NFEAT * DHEAD) + off];
    tile[jj * 65 + e] = s;
  }
  __syncthreads();
#pragma unroll
  for (int i = 0; i < 16; ++i) {
    int idx = t + i * 256;
    int e = idx >> 6, jj = idx & 63;
    float x = tile[jj * 65 + e];
    ushort h = bf16h(x);
    size_t o = ((size_t)head * DHEAD + e) * NFEAT + jb * 64 + jj;
    ctxThi[o] = h;
    ctxTlo[o] = bf16h(x - bf16f(h));
  }
}

// ---------------------------------------------------------------------------
// qout (unchanged from round 7 — passed, no longer top-5): two-pass
// streamed transpose-trick with unroll caps bounding the hoist window.
// ---------------------------------------------------------------------------
__global__ __launch_bounds__(512, 2) void qout_kernel(
    const float* __restrict__ qq, const ushort* __restrict__ P2hi,
    const ushort* __restrict__ P2lo, const float* __restrict__ ksum,
    const ushort* __restrict__ ctxThi, const ushort* __restrict__ ctxTlo,
    float* __restrict__ out) {
  __shared__ __align__(16) ushort PhiL[NFEAT * DHEAD];  // 32 KB
  __shared__ __align__(16) ushort PloL[NFEAT * DHEAD];  // 32 KB
  __shared__ __align__(16) ushort CTh[DHEAD * NFEAT];   // 32 KB (swizzled)
  __shared__ __align__(16) ushort CTl[DHEAD * NFEAT];   // 32 KB (swizzled)
  __shared__ float ksumL[NFEAT];                        // 1 KB
  const int t = threadIdx.x, lane = t & 63, w = t >> 6;
  const int cl = lane & 15, q = lane >> 4;
  const int head = blockIdx.x >> 3, slab = blockIdx.x & 7;
  for (int i = t; i < 2048; i += 512) {
    ((float4*)PhiL)[i] = ((const float4*)P2hi)[i];
    ((float4*)PloL)[i] = ((const float4*)P2lo)[i];
  }
  {  // stage ctxT with XOR swizzle (4-ushort groups stay contiguous)
    const size_t cb = (size_t)head * DHEAD * NFEAT;
    for (int g = t; g < 4096; g += 512) {
      int e = g >> 6, j4 = (g & 63) << 2;
      uint2 hv = *(const uint2*)(ctxThi + cb + e * NFEAT + j4);
      uint2 lv = *(const uint2*)(ctxTlo + cb + e * NFEAT + j4);
      int dst = e * NFEAT + (j4 ^ ((e & 15) << 2));
      *(uint2*)&CTh[dst] = hv;
      *(uint2*)&CTl[dst] = lv;
    }
  }
  if (t < NFEAT) ksumL[t] = ksum[head * NFEAT + t];
  __syncthreads();

  for (int s = 0; s < 4; ++s) {
    const int rb = slab * 512 + (w + s * 8) * 16;
    // B-frags: Q rows (col = n = cl), k = d
    const float* xb = qq + ((size_t)(head * NSEQ + rb + cl)) * DHEAD + q * 8;
    float4 pa0 = *(const float4*)(xb);
    float4 pa1 = *(const float4*)(xb + 4);
    float4 pa2 = *(const float4*)(xb + 32);
    float4 pa3 = *(const float4*)(xb + 36);
    float af[2][8] = {{pa0.x, pa0.y, pa0.z, pa0.w, pa1.x, pa1.y, pa1.z, pa1.w},
                      {pa2.x, pa2.y, pa2.z, pa2.w, pa3.x, pa3.y, pa3.z, pa3.w}};
    Frag8 bh[2], bl[2];
    float ssq = 0.f;
#pragma unroll
    for (int ks = 0; ks < 2; ++ks)
#pragma unroll
      for (int i = 0; i < 8; ++i) {
        float x = af[ks][i];
        ssq = fmaf(x, x, ssq);
        ushort h = bf16h(x);
        bh[ks].u[i] = h;
        bl[ks].u[i] = bf16h(x - bf16f(h));
      }
    float s2 = ssq;
    s2 += __shfl_xor(s2, 16);
    s2 += __shfl_xor(s2, 32);  // full ssq of row cl (lane-local diag)
    // ---- pass 1: hi-only row-max estimate (unroll-capped) ----
    float mr = -3.0e38f;
#pragma unroll 2
    for (int jt = 0; jt < 16; ++jt) {
      v4f a = (v4f){0.f, 0.f, 0.f, 0.f};
      a = MFMA32(*(const v8s*)&PhiL[((0 * 4 + q) * NFEAT + jt * 16 + cl) * 8],
                 bh[0].v, a);
      a = MFMA32(*(const v8s*)&PhiL[((1 * 4 + q) * NFEAT + jt * 16 + cl) * 8],
                 bh[1].v, a);
      mr = fmaxf(fmaxf(fmaxf(mr, a[0]), fmaxf(a[1], a[2])), a[3]);
    }
    mr = fmaxf(mr, __shfl_xor(mr, 16));
    mr = fmaxf(mr, __shfl_xor(mr, 32));
    const float mm = mr + DIAG_C * s2;
    // ---- pass 2: streamed dd -> qp -> PV (unroll 1: one jt tile live) ----
    v4f oacc[4];
#pragma unroll
    for (int et = 0; et < 4; ++et) oacc[et] = (v4f){0.f, 0.f, 0.f, 0.f};
    float ds = 0.f;
#pragma unroll 1
    for (int jt = 0; jt < 16; ++jt) {
      v4f aA = (v4f){0.f, 0.f, 0.f, 0.f};
      v4f aB = (v4f){0.f, 0.f, 0.f, 0.f};
      {
        const int p0 = ((0 * 4 + q) * NFEAT + jt * 16 + cl) * 8;
        const int p1 = ((1 * 4 + q) * NFEAT + jt * 16 + cl) * 8;
        v8s pAh0 = *(const v8s*)&PhiL[p0];
        v8s pAl0 = *(const v8s*)&PloL[p0];
        v8s pAh1 = *(const v8s*)&PhiL[p1];
        v8s pAl1 = *(const v8s*)&PloL[p1];
        aA = MFMA32(pAh0, bh[0].v, aA);
        aB = MFMA32(pAh1, bh[1].v, aB);
        aA = MFMA32(pAh0, bl[0].v, aA);
        aB = MFMA32(pAh1, bl[1].v, aB);
        aA = MFMA32(pAl0, bh[0].v, aA);
        aB = MFMA32(pAl1, bh[1].v, aB);
      }
      Frag4 qph, qpl;
#pragma unroll
      for (int r = 0; r < 4; ++r) {
        float a = aA[r] + aB[r];
        float qv = RATIO_C * (__expf(a - mm) + KEPS_C);
        ds = fmaf(qv, ksumL[jt * 16 + q * 4 + r], ds);
        ushort h = bf16h(qv);
        qph.u[r] = h;
        qpl.u[r] = bf16h(qv - bf16f(h));
      }
#pragma unroll
      for (int et = 0; et < 4; ++et) {
        const int ci = (et * 16 + cl) * NFEAT + ((jt * 16 + q * 4) ^ (cl << 2));
        v4s cth = *(const v4s*)&CTh[ci];
        v4s ctl = *(const v4s*)&CTl[ci];
        oacc[et] = MFMA16(cth, qph.v, oacc[et]);
        oacc[et] = MFMA16(cth, qpl.v, oacc[et]);
        oacc[et] = MFMA16(ctl, qph.v, oacc[et]);
      }
    }
    ds += __shfl_xor(ds, 16);
    ds += __shfl_xor(ds, 32);
    const float dinv = 1.0f / ds;
    // C: lane(cl,q) = outT[e=et*16+q*4+r][n=cl] -> float4 store per et
    float* ob = out + ((size_t)(head * NSEQ + rb + cl)) * DHEAD;
#pragma unroll
    for (int et = 0; et < 4; ++et) {
      float4 o;
      o.x = oacc[et][0] * dinv;
      o.y = oacc[et][1] * dinv;
      o.z = oacc[et][2] * dinv;
      o.w = oacc[et][3] * dinv;
      *(float4*)(ob + et * 16 + q * 4) = o;
    }
  }
}

extern "C" void kernel_launch(void* const* d_in, const int* in_sizes, int n_in,
                              void* d_out, int out_size, void* d_ws, size_t ws_size,
                              hipStream_t stream) {
  (void)in_sizes; (void)n_in; (void)out_size;
  const float* q = (const float*)d_in[0];
  const float* k = (const float*)d_in[1];
  const float* v = (const float*)d_in[2];
  const float* proj = (const float*)d_in[3];
  float* out = (float*)d_out;
  unsigned char* ws = (unsigned char*)d_ws;
  unsigned* kmax_u = (unsigned*)ws;                    // @0
  float* ksum = (float*)(ws + 256);                    // 32 KB
  float* ctx = (float*)(ws + 33024);                   // 2 MB (fallback only)
  ushort* P2hi = (ushort*)(ws + 2130176);              // 32 KB
  ushort* P2lo = (ushort*)(ws + 2162944);              // 32 KB
  ushort* ctxThi = (ushort*)(ws + 2195712);            // 1 MB
  ushort* ctxTlo = (ushort*)(ws + 3244288);            // 1 MB -> end 4292864
  float* ctxpart = (float*)(ws + 4292864);             // 16.78 MB (partials)
  const bool big_ws = ws_size >= (size_t)4292864 + (size_t)256 * NFEAT * DHEAD * 4;

  hipLaunchKernelGGL(prep_kernel, dim3(64), dim3(256), 0, stream, proj, P2hi, P2lo);
  if (big_ws) {
    // zero only kmax_u + ksum; ctx partials are written, not accumulated
    (void)hipMemsetAsync(d_ws, 0, 33024, stream);
    hipLaunchKernelGGL(kmax_kernel, dim3(512), dim3(512), 0, stream, k, P2hi,
                       kmax_u);
    hipLaunchKernelGGL(kctx_kernel_t<1>, dim3(256), dim3(512), 0, stream, k, v,
                       P2hi, P2lo, kmax_u, ksum, ctxpart);
    hipLaunchKernelGGL(ctxprep_red_kernel, dim3(128), dim3(256), 0, stream,
                       ctxpart, ctxThi, ctxTlo);
  } else {
    (void)hipMemsetAsync(d_ws, 0, 2130176, stream);  // kmax_u + ksum + ctx
    hipLaunchKernelGGL(kmax_kernel, dim3(512), dim3(512), 0, stream, k, P2hi,
                       kmax_u);
    hipLaunchKernelGGL(kctx_kernel_t<0>, dim3(256), dim3(512), 0, stream, k, v,
                       P2hi, P2lo, kmax_u, ksum, ctx);
    hipLaunchKernelGGL(ctxprep_kernel, dim3(128), dim3(256), 0, stream, ctx,
                       ctxThi, ctxTlo);
  }
  hipLaunchKernelGGL(qout_kernel, dim3(256), dim3(512), 0, stream, q, P2hi,
                     P2lo, ksum, ctxThi, ctxTlo, out);
}